// Round 6
// baseline (1238.306 us; speedup 1.0000x reference)
//
#include <hip/hip_runtime.h>
#include <hip/hip_bf16.h>
#include <math.h>

#define B_  256
#define T_  40
#define IN_ 2048
#define E_  512
#define H_  1024
#define V_  5000
#define G4_ 4096   // 4*H

typedef __bf16 bf16x8 __attribute__((ext_vector_type(8)));
typedef float  f32x4  __attribute__((ext_vector_type(4)));
typedef unsigned int u32x4 __attribute__((ext_vector_type(4)));

__device__ __forceinline__ float sigm_f(float x) { return 1.0f / (1.0f + __expf(-x)); }
__device__ __forceinline__ float tanh_f(float x) { return 1.0f - 2.0f / (1.0f + __expf(2.0f * x)); }
__device__ __forceinline__ float sigm(float x) { return 1.0f / (1.0f + expf(-x)); }

__device__ __forceinline__ unsigned short f2b(float x) {
    __hip_bfloat16 h = __float2bfloat16(x);
    return *reinterpret_cast<unsigned short*>(&h);
}

#define GLOAD_LDS(g, l) __builtin_amdgcn_global_load_lds(                     \
    (const __attribute__((address_space(1))) unsigned int*)(g),               \
    (__attribute__((address_space(3))) unsigned int*)(l), 16, 0, 0)

// LLC-coherent (cross-XCD) 16B load / 2B store
__device__ __forceinline__ void llc_load16(u32x4* dst, const unsigned short* p) {
    asm volatile("global_load_dwordx4 %0, %1, off sc0 sc1" : "=v"(*dst) : "v"(p));
}
__device__ __forceinline__ void llc_store2(unsigned short* p, unsigned short v) {
    unsigned int vv = v;
    asm volatile("global_store_short %0, %1, off sc0 sc1" :: "v"(p), "v"(vv) : "memory");
}
#define VM_WAIT(n) do {                                                       \
    asm volatile("s_waitcnt vmcnt(" #n ")" ::: "memory");                     \
    __builtin_amdgcn_sched_barrier(0);                                        \
} while (0)

// ---------------------------------------------------------------------------
// bf16 MFMA GEMM: C[M,N](f32) = gather(A) @ B^T + bias[N]
//                 + addMat[(row & rowMask)*addStride + col]
// 128x128 tile, BK=32, 256 thr = 4 waves, 16x16x32 MFMA.
// ---------------------------------------------------------------------------
__global__ __launch_bounds__(256) void gemm_mfma(
    const unsigned short* __restrict__ A, int lda,
    const int* __restrict__ gidx,
    const unsigned short* __restrict__ Bm, int ldb,
    const float* __restrict__ bias,
    const float* __restrict__ addMat, int rowMask, long long addStride,
    float* __restrict__ C, int ldc, int N, int K)
{
    __shared__ unsigned short As[128 * 32];
    __shared__ unsigned short Bs[128 * 32];

    const int tid  = threadIdx.x;
    const int wave = tid >> 6, lane = tid & 63;
    const int brow0 = blockIdx.y * 128, bcol0 = blockIdx.x * 128;
    const int wrow0 = (wave >> 1) * 64, wcol0 = (wave & 1) * 64;

    const int srow = lane >> 2;
    const int scol = (lane & 3) * 8;
    const unsigned short* pA[2];
    const unsigned short* pB[2];
    unsigned short* lA[2];
    unsigned short* lB[2];
    #pragma unroll
    for (int i = 0; i < 2; ++i) {
        int seg = wave * 2 + i;
        int row = seg * 16 + srow;
        long long ar = gidx ? (long long)gidx[brow0 + row] : (long long)(brow0 + row);
        pA[i] = A + ar * lda + scol;
        pB[i] = Bm + (long long)(bcol0 + row) * ldb + scol;
        lA[i] = &As[seg * 16 * 32];
        lB[i] = &Bs[seg * 16 * 32];
    }

    f32x4 acc[4][4] = {};
    const int foff = (lane & 15) * 32 + (lane >> 4) * 8;

    for (int k0 = 0; k0 < K; k0 += 32) {
        GLOAD_LDS(pA[0] + k0, lA[0]);
        GLOAD_LDS(pA[1] + k0, lA[1]);
        GLOAD_LDS(pB[0] + k0, lB[0]);
        GLOAD_LDS(pB[1] + k0, lB[1]);
        __syncthreads();

        bf16x8 a[4], b[4];
        #pragma unroll
        for (int m = 0; m < 4; ++m)
            a[m] = *(const bf16x8*)&As[(wrow0 + m * 16) * 32 + foff];
        #pragma unroll
        for (int n = 0; n < 4; ++n)
            b[n] = *(const bf16x8*)&Bs[(wcol0 + n * 16) * 32 + foff];
        #pragma unroll
        for (int m = 0; m < 4; ++m)
            #pragma unroll
            for (int n = 0; n < 4; ++n)
                acc[m][n] = __builtin_amdgcn_mfma_f32_16x16x32_bf16(
                    a[m], b[n], acc[m][n], 0, 0, 0);
        __syncthreads();
    }

    #pragma unroll
    for (int m = 0; m < 4; ++m) {
        #pragma unroll
        for (int j = 0; j < 4; ++j) {
            int row = brow0 + wrow0 + m * 16 + (lane >> 4) * 4 + j;
            const float* addRow = addMat
                ? addMat + (long long)(row & rowMask) * addStride : nullptr;
            #pragma unroll
            for (int n = 0; n < 4; ++n) {
                int col = bcol0 + wcol0 + n * 16 + (lane & 15);
                if (col < N) {
                    float v = acc[m][n][j];
                    if (bias)   v += bias[col];
                    if (addRow) v += addRow[col];
                    C[(long long)row * ldc + col] = v;
                }
            }
        }
    }
}

// ---------------------------------------------------------------------------
// Persistent LSTM recurrence (plain launch, 256 WGs x 256 thr, co-resident).
// WG (mb = bid>>6, hb = bid&63): batch rows mb*64..+64, h-cols hb*16..+16
// (gate cols {q*1024 + hb*16 + r}, q = 0..3 -> i/f/g/o quad per lane).
// W_hh slice [64 gate-rows x 1024 K] bf16 LDS-resident (128 KB, XOR-swizzled),
// staged ONCE. c-state in VGPRs across all 40 steps. h passes between steps
// through the coherent LLC (sc0 sc1 loads/stores); per-step sync is one
// agent-scope atomic counter + one spinner thread per WG. No L2 invalidates.
// ---------------------------------------------------------------------------
__global__ __launch_bounds__(256) void recur_persist(
    unsigned short* __restrict__ hs,          // slots 1..40 = h_1..h_40 [B,H] bf16
    const unsigned short* __restrict__ Whh,   // [4096,1024] bf16
    const float* __restrict__ gates,          // [T, B, 4H] f32
    unsigned int* __restrict__ done)          // [T+1], zeroed
{
    extern __shared__ unsigned short lds[];   // [64][1024] bf16 = 128 KB

    const int tid = threadIdx.x;
    const int w = tid >> 6, lane = tid & 63;
    const int mb = blockIdx.x >> 6;           // 0..3
    const int hb = blockIdx.x & 63;           // 0..63
    const int r16 = lane & 15, g4 = lane >> 4;
    const int sw7 = r16 & 7;

    // ---- stage W_hh slice into LDS once (wave w stages gate q=w's 16 rows) --
    // LDS layout: row g = q*16 + hl (2048 B each); 16B-granule G of row g holds
    // k-granule G ^ (g&7)  (bank-conflict-free ds_read_b128 afterwards).
    {
        const int q = w;
        for (int r = 0; r < 16; ++r) {
            const int g = q * 16 + r;
            const unsigned short* rowsrc =
                Whh + ((size_t)q * 1024 + hb * 16 + r) * H_;
            #pragma unroll
            for (int half = 0; half < 2; ++half) {
                int gran = (half * 64 + lane) ^ (g & 7);
                GLOAD_LDS(rowsrc + gran * 8, &lds[g * 1024 + half * 512]);
            }
        }
    }
    asm volatile("s_waitcnt vmcnt(0)" ::: "memory");
    __syncthreads();

    // per-lane coordinates
    const size_t a_off = ((size_t)(mb * 64 + w * 16 + r16) << 10) + (g4 << 3);
    const int orow0 = mb * 64 + w * 16 + g4 * 4;     // output rows (4: +j)
    const int hc    = hb * 16 + r16;                 // h column
    const size_t g_off = ((size_t)orow0 << 12) + hc; // + q*1024 + j*4096

    int qbase[4];
    #pragma unroll
    for (int q = 0; q < 4; ++q) qbase[q] = (q * 16 + r16) << 11;

    float cc[4];
    const size_t BH = (size_t)B_ * H_;

    // ---- step 0: h0 = 0 -> gates only ----
    {
        float gv[4][4];
        #pragma unroll
        for (int j = 0; j < 4; ++j) {
            const float* gp = gates + g_off + (size_t)j * G4_;
            #pragma unroll
            for (int q = 0; q < 4; ++q) gv[q][j] = gp[q << 10];
        }
        unsigned short* hw = hs + BH + ((size_t)orow0 << 10) + hc;
        #pragma unroll
        for (int j = 0; j < 4; ++j) {
            float c2 = sigm_f(gv[0][j]) * tanh_f(gv[2][j]);
            cc[j] = c2;
            llc_store2(hw + ((size_t)j << 10), f2b(sigm_f(gv[3][j]) * tanh_f(c2)));
        }
        asm volatile("s_waitcnt vmcnt(0)" ::: "memory");
        __syncthreads();
        if (tid == 0) {
#if __has_builtin(__builtin_amdgcn_buffer_wbl2)
            __builtin_amdgcn_buffer_wbl2();
#else
            asm volatile("buffer_wbl2" ::: "memory");
#endif
            asm volatile("s_waitcnt vmcnt(0)" ::: "memory");
            __hip_atomic_fetch_add(&done[1], 1u, __ATOMIC_RELAXED,
                                   __HIP_MEMORY_SCOPE_AGENT);
        }
    }

    // ---- steps 1..39 ----
    for (int t = 1; t < T_; ++t) {
        // gates for this step (independent of h -> issued before the spin)
        float gv[4][4];
        #pragma unroll
        for (int j = 0; j < 4; ++j) {
            const float* gp = gates + (size_t)t * (B_ * G4_) + g_off + (size_t)j * G4_;
            #pragma unroll
            for (int q = 0; q < 4; ++q) gv[q][j] = gp[q << 10];
        }

        // wait for h-slot t to be complete chip-wide
        if (tid == 0) {
            while (__hip_atomic_load(&done[t], __ATOMIC_RELAXED,
                                     __HIP_MEMORY_SCOPE_AGENT) < 256u)
                __builtin_amdgcn_s_sleep(2);
        }
        __syncthreads();
        asm volatile("s_waitcnt vmcnt(0)" ::: "memory");  // drain gv loads
        __builtin_amdgcn_sched_barrier(0);

        const unsigned short* hp = hs + (size_t)t * BH + a_off;

        u32x4 a0[8], a1[8];
        #pragma unroll
        for (int u = 0; u < 8; ++u) llc_load16(&a0[u], hp + u * 32);
        #pragma unroll
        for (int u = 0; u < 8; ++u) llc_load16(&a1[u], hp + (8 + u) * 32);

        f32x4 acc[4] = {};

#define DO_CHUNK(BUF, KSB)                                                    \
        _Pragma("unroll")                                                     \
        for (int u = 0; u < 8; ++u) {                                         \
            bf16x8 a8 = __builtin_bit_cast(bf16x8, BUF[u]);                   \
            _Pragma("unroll")                                                 \
            for (int q = 0; q < 4; ++q) {                                     \
                int off = qbase[q] + (((((KSB) + u) * 4 + g4) ^ sw7) << 4);   \
                bf16x8 b8 = *(const bf16x8*)((const char*)lds + off);         \
                acc[q] = __builtin_amdgcn_mfma_f32_16x16x32_bf16(             \
                    a8, b8, acc[q], 0, 0, 0);                                 \
            }                                                                 \
        }

        VM_WAIT(8);
        DO_CHUNK(a0, 0)
        #pragma unroll
        for (int u = 0; u < 8; ++u) llc_load16(&a0[u], hp + (16 + u) * 32);
        VM_WAIT(8);
        DO_CHUNK(a1, 8)
        #pragma unroll
        for (int u = 0; u < 8; ++u) llc_load16(&a1[u], hp + (24 + u) * 32);
        VM_WAIT(8);
        DO_CHUNK(a0, 16)
        VM_WAIT(0);
        DO_CHUNK(a1, 24)
#undef DO_CHUNK

        // ---- fused cell ----
        unsigned short* hw = hs + (size_t)(t + 1) * BH + ((size_t)orow0 << 10) + hc;
        #pragma unroll
        for (int j = 0; j < 4; ++j) {
            float gi = acc[0][j] + gv[0][j];
            float gf = acc[1][j] + gv[1][j];
            float gg = acc[2][j] + gv[2][j];
            float go = acc[3][j] + gv[3][j];
            float c2 = sigm_f(gf) * cc[j] + sigm_f(gi) * tanh_f(gg);
            cc[j] = c2;
            llc_store2(hw + ((size_t)j << 10), f2b(sigm_f(go) * tanh_f(c2)));
        }
        asm volatile("s_waitcnt vmcnt(0)" ::: "memory");
        __syncthreads();
        if (tid == 0) {
#if __has_builtin(__builtin_amdgcn_buffer_wbl2)
            __builtin_amdgcn_buffer_wbl2();
#else
            asm volatile("buffer_wbl2" ::: "memory");
#endif
            asm volatile("s_waitcnt vmcnt(0)" ::: "memory");
            __hip_atomic_fetch_add(&done[t + 1], 1u, __ATOMIC_RELAXED,
                                   __HIP_MEMORY_SCOPE_AGENT);
        }
    }
}

// ---------------------------------------------------------------------------
// fp32 tiled GEMM (two small GEMMs): C = A @ B^T + bias
// ---------------------------------------------------------------------------
__global__ __launch_bounds__(256) void gemm_bt(
    const float* __restrict__ A, int lda,
    const float* __restrict__ Bm, int ldb,
    const float* __restrict__ bias,
    float* __restrict__ C, int ldc, int N, int K)
{
    const int BK = 16;
    __shared__ float As[BK][64];
    __shared__ float Bs[BK][64];

    const int tx = threadIdx.x, ty = threadIdx.y;
    const int tid = ty * 16 + tx;
    const int brow0 = blockIdx.y * 64;
    const int bcol0 = blockIdx.x * 64;

    const int e0   = tid * 4;
    const int la_r = e0 / BK;
    const int la_k = e0 % BK;

    const long long arow_base = (long long)(brow0 + la_r) * lda;
    const int bRowG = bcol0 + la_r;
    const bool bValid = (bRowG < N);
    const long long brow_base = (long long)bRowG * ldb;

    float acc[4][4] = {};

    for (int k0 = 0; k0 < K; k0 += BK) {
        float4 av = *(const float4*)(A + arow_base + k0 + la_k);
        float4 bv = make_float4(0.f, 0.f, 0.f, 0.f);
        if (bValid) bv = *(const float4*)(Bm + brow_base + k0 + la_k);

        As[la_k + 0][la_r] = av.x; As[la_k + 1][la_r] = av.y;
        As[la_k + 2][la_r] = av.z; As[la_k + 3][la_r] = av.w;
        Bs[la_k + 0][la_r] = bv.x; Bs[la_k + 1][la_r] = bv.y;
        Bs[la_k + 2][la_r] = bv.z; Bs[la_k + 3][la_r] = bv.w;
        __syncthreads();

        #pragma unroll
        for (int kk = 0; kk < BK; ++kk) {
            float af[4], bf[4];
            #pragma unroll
            for (int i = 0; i < 4; ++i) af[i] = As[kk][ty * 4 + i];
            #pragma unroll
            for (int j = 0; j < 4; ++j) bf[j] = Bs[kk][tx * 4 + j];
            #pragma unroll
            for (int i = 0; i < 4; ++i)
                #pragma unroll
                for (int j = 0; j < 4; ++j)
                    acc[i][j] = fmaf(af[i], bf[j], acc[i][j]);
        }
        __syncthreads();
    }

    #pragma unroll
    for (int i = 0; i < 4; ++i) {
        const int row = brow0 + ty * 4 + i;
        #pragma unroll
        for (int j = 0; j < 4; ++j) {
            const int col = bcol0 + tx * 4 + j;
            if (col < N) {
                float v = acc[i][j];
                if (bias) v += bias[col];
                C[(long long)row * ldc + col] = v;
            }
        }
    }
}

// ---------------------------------------------------------------------------
// f32 -> bf16 conversion with optional column slice + zero row padding
// ---------------------------------------------------------------------------
__global__ void conv2bf(const float* __restrict__ src, unsigned short* __restrict__ dst,
                        int rows, int rowsPad, int cols, int srcld, int srccol0)
{
    int i = blockIdx.x * blockDim.x + threadIdx.x;
    int c4n = cols >> 2;
    if (i >= rowsPad * c4n) return;
    int r = i / c4n, c4 = i % c4n;
    ushort4 o;
    if (r < rows) {
        float4 v = *(const float4*)(src + (long long)r * srcld + srccol0 + c4 * 4);
        o.x = f2b(v.x); o.y = f2b(v.y); o.z = f2b(v.z); o.w = f2b(v.w);
    } else {
        o = make_ushort4(0, 0, 0, 0);
    }
    *(ushort4*)(dst + (long long)r * cols + c4 * 4) = o;
}

// ---------------------------------------------------------------------------
// prep: gather indices + combined bias
// idxEmb ordered for gates rows r = t*B + b (gates layout [T, B, 4H])
// idxLog ordered for logits rows r = b*T + t
// ---------------------------------------------------------------------------
__global__ void prep_kernel(const int* __restrict__ labels,
                            const float* __restrict__ b_ih,
                            const float* __restrict__ b_hh,
                            int* __restrict__ idxEmb,
                            int* __restrict__ idxLog,
                            float* __restrict__ bsum)
{
    int r = blockIdx.x * blockDim.x + threadIdx.x;
    if (r < B_ * T_) {
        {   // embedding gather: r = t*B + b
            int t = r >> 8, b = r & (B_ - 1);
            int tsrc = (t == 0) ? (T_ - 1) : (t - 1);
            idxEmb[r] = labels[b * T_ + tsrc];
        }
        {   // logits gather: r = b*T + t  -> hs slot t+1
            int b = r / T_, t = r % T_;
            idxLog[r] = (t + 1) * B_ + b;
        }
    }
    if (r < G4_) bsum[r] = b_ih[r] + b_hh[r];
}

extern "C" void kernel_launch(void* const* d_in, const int* in_sizes, int n_in,
                              void* d_out, int out_size, void* d_ws, size_t ws_size,
                              hipStream_t stream)
{
    const float* X      = (const float*)d_in[0];
    const int*   labels = (const int*)  d_in[1];
    const float* W_f    = (const float*)d_in[2];
    const float* b_f    = (const float*)d_in[3];
    const float* emb    = (const float*)d_in[4];
    const float* W_ih   = (const float*)d_in[5];
    const float* W_hh   = (const float*)d_in[6];
    const float* b_ih   = (const float*)d_in[7];
    const float* b_hh   = (const float*)d_in[8];
    const float* W_out  = (const float*)d_in[9];
    const float* b_out  = (const float*)d_in[10];
    float* out = (float*)d_out;
    (void)in_sizes; (void)n_in; (void)out_size; (void)ws_size;

    char* ws = (char*)d_ws;
    size_t off = 0;
    auto alloc = [&](size_t bytes) {
        void* p = ws + off;
        off += (bytes + 255) & ~(size_t)255;
        return p;
    };
    unsigned short* emb_bf  = (unsigned short*)alloc((size_t)(V_ + 1) * E_ * 2);
    unsigned short* WihE_bf = (unsigned short*)alloc((size_t)G4_ * E_ * 2);
    unsigned short* Whh_bf  = (unsigned short*)alloc((size_t)G4_ * H_ * 2);
    unsigned short* Wout_bf = (unsigned short*)alloc((size_t)5120 * H_ * 2);
    unsigned short* hs_bf   = (unsigned short*)alloc((size_t)(T_ + 1) * B_ * H_ * 2);
    float* features = (float*)alloc(B_ * E_ * 4);
    float* bsum     = (float*)alloc(G4_ * 4);
    int*   idxEmb   = (int*)  alloc(B_ * T_ * 4);
    int*   idxLog   = (int*)  alloc(B_ * T_ * 4);
    unsigned int* done = (unsigned int*)alloc(64 * 4);

    // d_out reuse: gates [T,B,4H] at the front (fully consumed by the
    // recurrence before the logits GEMM overwrites d_out); baseMat in tail.
    float* gates   = out;
    float* baseMat = out + (size_t)B_ * T_ * G4_;   // 41.94M + 1.05M < 51.2M

    hipMemsetAsync(done, 0, 64 * 4, stream);        // step flags = 0

    prep_kernel<<<(B_ * T_ + 255) / 256, 256, 0, stream>>>(
        labels, b_ih, b_hh, idxEmb, idxLog, bsum);

    {
        int n;
        n = (V_ + 1) * E_ / 4;
        conv2bf<<<(n + 255) / 256, 256, 0, stream>>>(emb, emb_bf, V_ + 1, V_ + 1, E_, E_, 0);
        n = G4_ * E_ / 4;
        conv2bf<<<(n + 255) / 256, 256, 0, stream>>>(W_ih, WihE_bf, G4_, G4_, E_, 2 * E_, E_);
        n = G4_ * H_ / 4;
        conv2bf<<<(n + 255) / 256, 256, 0, stream>>>(W_hh, Whh_bf, G4_, G4_, H_, H_, 0);
        n = 5120 * H_ / 4;
        conv2bf<<<(n + 255) / 256, 256, 0, stream>>>(W_out, Wout_bf, V_, 5120, H_, H_, 0);
    }

    dim3 thr(16, 16);

    // features = X @ W_f^T + b_f            [256,512] K=2048 (fp32)
    gemm_bt<<<dim3(E_ / 64, B_ / 64), thr, 0, stream>>>(
        X, IN_, W_f, IN_, b_f, features, E_, E_, IN_);

    // base = features @ W_ih[:, :E]^T + (b_ih + b_hh)   [256,4096] K=512 (fp32)
    gemm_bt<<<dim3(G4_ / 64, B_ / 64), thr, 0, stream>>>(
        features, E_, W_ih, 2 * E_, bsum, baseMat, G4_, G4_, E_);

    // gates[t,b,:] = gather(emb_bf) @ WihE^T + base[b]   [10240,4096] K=512
    gemm_mfma<<<dim3(G4_ / 128, (B_ * T_) / 128), 256, 0, stream>>>(
        emb_bf, E_, idxEmb, WihE_bf, E_, nullptr,
        baseMat, B_ - 1, G4_, gates, G4_, G4_, E_);

    // ---- persistent recurrence (all 40 steps, one plain launch) ----
    {
        hipFuncSetAttribute((const void*)recur_persist,
                            hipFuncAttributeMaxDynamicSharedMemorySize, 131072);
        recur_persist<<<256, 256, 131072, stream>>>(hs_bf, Whh_bf, gates, done);
    }

    // logits = gather(hs_bf) @ W_out^T + b_out   [10240,5000] K=1024 (MFMA)
    gemm_mfma<<<dim3(5120 / 128, (B_ * T_) / 128), 256, 0, stream>>>(
        hs_bf, H_, idxLog, Wout_bf, H_, b_out,
        nullptr, 0, 0, out, V_, V_, H_);
}

// Round 7
// 1092.194 us; speedup vs baseline: 1.1338x; 1.1338x over previous
//
#include <hip/hip_runtime.h>
#include <hip/hip_bf16.h>
#include <math.h>

#define B_  256
#define T_  40
#define IN_ 2048
#define E_  512
#define H_  1024
#define V_  5000
#define G4_ 4096   // 4*H

typedef __bf16 bf16x8 __attribute__((ext_vector_type(8)));
typedef float  f32x4  __attribute__((ext_vector_type(4)));
typedef unsigned int u32x4 __attribute__((ext_vector_type(4)));

__device__ __forceinline__ float sigm_f(float x) { return 1.0f / (1.0f + __expf(-x)); }
__device__ __forceinline__ float tanh_f(float x) { return 1.0f - 2.0f / (1.0f + __expf(2.0f * x)); }

__device__ __forceinline__ unsigned short f2b(float x) {
    __hip_bfloat16 h = __float2bfloat16(x);
    return *reinterpret_cast<unsigned short*>(&h);
}

#define GLOAD_LDS(g, l) __builtin_amdgcn_global_load_lds(                     \
    (const __attribute__((address_space(1))) unsigned int*)(g),               \
    (__attribute__((address_space(3))) unsigned int*)(l), 16, 0, 0)

// LLC-coherent (cross-XCD) 16B load / 16B store
__device__ __forceinline__ void llc_load16(u32x4* dst, const unsigned short* p) {
    asm volatile("global_load_dwordx4 %0, %1, off sc0 sc1" : "=v"(*dst) : "v"(p));
}
__device__ __forceinline__ void llc_store16(unsigned short* p, u32x4 v) {
    asm volatile("global_store_dwordx4 %0, %1, off sc0 sc1" :: "v"(p), "v"(v) : "memory");
}
#define VM_WAIT(n) do {                                                       \
    asm volatile("s_waitcnt vmcnt(" #n ")" ::: "memory");                     \
    __builtin_amdgcn_sched_barrier(0);                                        \
} while (0)

// ---------------------------------------------------------------------------
// bf16 MFMA GEMM: C[M,N](f32) = gather(A) @ B^T + bias[N]
//                 + addMat[(row & rowMask)*addStride + col]
// aBlocked: A stored as [kblk][256 rows][16] blocks (hs layout); gidx gives
//           ar with ar*16 = element offset of (row, k=0).
// permuteC: store col' = (col%1024)*4 + col/1024  (gates [B][1024][4] layout).
// 128x128 tile, BK=32, 256 thr = 4 waves, 16x16x32 MFMA.
// ---------------------------------------------------------------------------
__global__ __launch_bounds__(256) void gemm_mfma(
    const unsigned short* __restrict__ A, int lda, int aBlocked,
    const int* __restrict__ gidx,
    const unsigned short* __restrict__ Bm, int ldb,
    const float* __restrict__ bias,
    const float* __restrict__ addMat, int rowMask, long long addStride,
    float* __restrict__ C, int ldc, int permuteC, int N, int K)
{
    __shared__ unsigned short As[128 * 32];
    __shared__ unsigned short Bs[128 * 32];

    const int tid  = threadIdx.x;
    const int wave = tid >> 6, lane = tid & 63;
    const int brow0 = blockIdx.y * 128, bcol0 = blockIdx.x * 128;
    const int wrow0 = (wave >> 1) * 64, wcol0 = (wave & 1) * 64;

    const int srow = lane >> 2;
    const int scol = (lane & 3) * 8;
    const size_t kstep = aBlocked ? 256 : 1;
    const unsigned short* pA[2];
    const unsigned short* pB[2];
    unsigned short* lA[2];
    unsigned short* lB[2];
    #pragma unroll
    for (int i = 0; i < 2; ++i) {
        int seg = wave * 2 + i;
        int row = seg * 16 + srow;
        long long ar = gidx ? (long long)gidx[brow0 + row] : (long long)(brow0 + row);
        if (aBlocked)
            pA[i] = A + ((size_t)ar << 4) + ((size_t)(scol >> 4) << 12) + (scol & 8);
        else
            pA[i] = A + (size_t)ar * lda + scol;
        pB[i] = Bm + (long long)(bcol0 + row) * ldb + scol;
        lA[i] = &As[seg * 16 * 32];
        lB[i] = &Bs[seg * 16 * 32];
    }

    f32x4 acc[4][4] = {};
    const int foff = (lane & 15) * 32 + (lane >> 4) * 8;

    for (int k0 = 0; k0 < K; k0 += 32) {
        GLOAD_LDS(pA[0] + (size_t)k0 * kstep, lA[0]);
        GLOAD_LDS(pA[1] + (size_t)k0 * kstep, lA[1]);
        GLOAD_LDS(pB[0] + k0, lB[0]);
        GLOAD_LDS(pB[1] + k0, lB[1]);
        __syncthreads();

        bf16x8 a[4], b[4];
        #pragma unroll
        for (int m = 0; m < 4; ++m)
            a[m] = *(const bf16x8*)&As[(wrow0 + m * 16) * 32 + foff];
        #pragma unroll
        for (int n = 0; n < 4; ++n)
            b[n] = *(const bf16x8*)&Bs[(wcol0 + n * 16) * 32 + foff];
        #pragma unroll
        for (int m = 0; m < 4; ++m)
            #pragma unroll
            for (int n = 0; n < 4; ++n)
                acc[m][n] = __builtin_amdgcn_mfma_f32_16x16x32_bf16(
                    a[m], b[n], acc[m][n], 0, 0, 0);
        __syncthreads();
    }

    #pragma unroll
    for (int m = 0; m < 4; ++m) {
        #pragma unroll
        for (int j = 0; j < 4; ++j) {
            int row = brow0 + wrow0 + m * 16 + (lane >> 4) * 4 + j;
            const float* addRow = addMat
                ? addMat + (long long)(row & rowMask) * addStride : nullptr;
            #pragma unroll
            for (int n = 0; n < 4; ++n) {
                int col = bcol0 + wcol0 + n * 16 + (lane & 15);
                if (col < N) {
                    float v = acc[m][n][j];
                    if (bias)   v += bias[col];
                    if (addRow) v += addRow[col];
                    int cidx = permuteC ? (((col & 1023) << 2) | (col >> 10)) : col;
                    C[(long long)row * ldc + cidx] = v;
                }
            }
        }
    }
}

// ---------------------------------------------------------------------------
// Persistent LSTM recurrence v2 (plain launch, 256 WGs x 256 thr).
// WG (mb = bid>>6, hb = bid&63): batch rows mb*64..+64, h-cols hb*16..+16.
// W_hh slice [64 gate-rows x 1024] bf16 LDS-resident (128 KB, XOR-swizzled).
// h stored BLOCKED: slot t = [64 kblk][256 row][16], so each WG's per-step
// output tile is one contiguous 2 KB span -> 128 coalesced 16B sc0sc1 stores
// (staged through 3 KB LDS). gates PERMUTED [T][B][1024][4] -> one float4
// per (row) holds the i/f/g/o quad. Sync: per-(step, mb) counter, 64
// producers; no buffer_wbl2 (vmcnt(0)-ack'd sc0sc1 stores + atomic order).
// ---------------------------------------------------------------------------
__global__ __launch_bounds__(256) void recur_persist(
    unsigned short* __restrict__ hs,          // slots 1..40, each 262144 elems
    const unsigned short* __restrict__ Whh,   // [4096,1024] bf16
    const float* __restrict__ gates,          // [T,B,1024,4] f32 (permuted)
    unsigned int* __restrict__ done)          // [(T+1)*4], zeroed
{
    extern __shared__ unsigned short lds[];   // [64][1024] bf16 = 128 KB
    __shared__ unsigned short hstage[64][24]; // store-coalescing scratch

    const int tid = threadIdx.x;
    const int w = tid >> 6, lane = tid & 63;
    const int mb = blockIdx.x >> 6;           // 0..3
    const int hb = blockIdx.x & 63;           // 0..63
    const int r16 = lane & 15, g4 = lane >> 4;
    const int sw7 = r16 & 7;
    const size_t SLOT = 262144;               // 64*256*16

    // ---- stage W_hh slice into LDS once (wave w = gate q) ----
    {
        const int q = w;
        for (int r = 0; r < 16; ++r) {
            const int g = q * 16 + r;
            const unsigned short* rowsrc =
                Whh + ((size_t)q * 1024 + hb * 16 + r) * H_;
            #pragma unroll
            for (int half = 0; half < 2; ++half) {
                int gran = (half * 64 + lane) ^ (g & 7);
                GLOAD_LDS(rowsrc + gran * 8, &lds[g * 1024 + half * 512]);
            }
        }
    }
    asm volatile("s_waitcnt vmcnt(0)" ::: "memory");
    __syncthreads();

    // per-lane coordinates
    const int arow = mb * 64 + w * 16 + r16;         // A row (blocked layout)
    const size_t abase = ((size_t)arow << 4) + ((g4 >> 1) << 12) + ((g4 & 1) << 3);
    const int orow0 = mb * 64 + w * 16 + g4 * 4;     // output rows +j
    const int hc    = hb * 16 + r16;                 // h column
    const int lrow0 = w * 16 + g4 * 4;               // local tile row

    int qbase[4];
    #pragma unroll
    for (int q = 0; q < 4; ++q) qbase[q] = (q * 16 + r16) << 11;

    float cc[4];

    // store path (shared): stage tile in LDS, 16B-coalesced sc0sc1 stores
    #define STORE_H(T1, HV)                                                   \
    {                                                                         \
        _Pragma("unroll")                                                     \
        for (int j = 0; j < 4; ++j) hstage[lrow0 + j][r16] = HV[j];           \
        __syncthreads();                                                      \
        if (tid < 128) {                                                      \
            u32x4 v = *(const u32x4*)&hstage[tid >> 1][(tid & 1) * 8];        \
            unsigned short* dst = hs + (size_t)(T1) * SLOT +                  \
                (((size_t)hb * 256 + mb * 64) << 4) + (size_t)tid * 8;        \
            llc_store16(dst, v);                                              \
        }                                                                     \
        asm volatile("s_waitcnt vmcnt(0)" ::: "memory");                      \
        __syncthreads();                                                      \
        if (tid == 0)                                                         \
            __hip_atomic_fetch_add(&done[(T1) * 4 + mb], 1u,                  \
                __ATOMIC_RELAXED, __HIP_MEMORY_SCOPE_AGENT);                  \
    }

    // ---- step 0: h0 = 0 -> gates only ----
    {
        unsigned short hv[4];
        #pragma unroll
        for (int j = 0; j < 4; ++j) {
            f32x4 gq = *(const f32x4*)(gates + ((size_t)(orow0 + j) << 12) + (hc << 2));
            float c2 = sigm_f(gq[0]) * tanh_f(gq[2]);
            cc[j] = c2;
            hv[j] = f2b(sigm_f(gq[3]) * tanh_f(c2));
        }
        STORE_H(1, hv)
    }

    // ---- steps 1..39 ----
    for (int t = 1; t < T_; ++t) {
        // gates for this step (independent of h -> issued before the spin)
        f32x4 gq[4];
        #pragma unroll
        for (int j = 0; j < 4; ++j)
            gq[j] = *(const f32x4*)(gates +
                ((size_t)(t * B_ + orow0 + j) << 12) + (hc << 2));

        // wait for h-slot t rows [mb*64, +64) complete
        if (tid == 0) {
            while (__hip_atomic_load(&done[t * 4 + mb], __ATOMIC_RELAXED,
                                     __HIP_MEMORY_SCOPE_AGENT) < 64u)
                __builtin_amdgcn_s_sleep(1);
        }
        __syncthreads();
        asm volatile("s_waitcnt vmcnt(0)" ::: "memory");
        __builtin_amdgcn_sched_barrier(0);

        const unsigned short* hp = hs + (size_t)t * SLOT + abase;

        u32x4 a0[8], a1[8];
        #pragma unroll
        for (int u = 0; u < 8; ++u) llc_load16(&a0[u], hp + (size_t)u * 8192);
        #pragma unroll
        for (int u = 0; u < 8; ++u) llc_load16(&a1[u], hp + (size_t)(8 + u) * 8192);

        f32x4 acc[4] = {};

#define DO_CHUNK(BUF, KSB)                                                    \
        _Pragma("unroll")                                                     \
        for (int u = 0; u < 8; ++u) {                                         \
            bf16x8 a8 = __builtin_bit_cast(bf16x8, BUF[u]);                   \
            _Pragma("unroll")                                                 \
            for (int q = 0; q < 4; ++q) {                                     \
                int off = qbase[q] + (((((KSB) + u) * 4 + g4) ^ sw7) << 4);   \
                bf16x8 b8 = *(const bf16x8*)((const char*)lds + off);         \
                acc[q] = __builtin_amdgcn_mfma_f32_16x16x32_bf16(             \
                    a8, b8, acc[q], 0, 0, 0);                                 \
            }                                                                 \
        }

        VM_WAIT(8);
        DO_CHUNK(a0, 0)
        #pragma unroll
        for (int u = 0; u < 8; ++u) llc_load16(&a0[u], hp + (size_t)(16 + u) * 8192);
        VM_WAIT(8);
        DO_CHUNK(a1, 8)
        #pragma unroll
        for (int u = 0; u < 8; ++u) llc_load16(&a1[u], hp + (size_t)(24 + u) * 8192);
        VM_WAIT(8);
        DO_CHUNK(a0, 16)
        VM_WAIT(0);
        DO_CHUNK(a1, 24)
#undef DO_CHUNK

        // ---- fused cell ----
        unsigned short hv[4];
        #pragma unroll
        for (int j = 0; j < 4; ++j) {
            float gi = acc[0][j] + gq[j][0];
            float gf = acc[1][j] + gq[j][1];
            float gg = acc[2][j] + gq[j][2];
            float go = acc[3][j] + gq[j][3];
            float c2 = sigm_f(gf) * cc[j] + sigm_f(gi) * tanh_f(gg);
            cc[j] = c2;
            hv[j] = f2b(sigm_f(go) * tanh_f(c2));
        }
        STORE_H(t + 1, hv)
    }
    #undef STORE_H
}

// ---------------------------------------------------------------------------
// fp32 tiled GEMM (two small GEMMs): C = A @ B^T + bias
// ---------------------------------------------------------------------------
__global__ __launch_bounds__(256) void gemm_bt(
    const float* __restrict__ A, int lda,
    const float* __restrict__ Bm, int ldb,
    const float* __restrict__ bias,
    float* __restrict__ C, int ldc, int N, int K)
{
    const int BK = 16;
    __shared__ float As[BK][64];
    __shared__ float Bs[BK][64];

    const int tx = threadIdx.x, ty = threadIdx.y;
    const int tid = ty * 16 + tx;
    const int brow0 = blockIdx.y * 64;
    const int bcol0 = blockIdx.x * 64;

    const int e0   = tid * 4;
    const int la_r = e0 / BK;
    const int la_k = e0 % BK;

    const long long arow_base = (long long)(brow0 + la_r) * lda;
    const int bRowG = bcol0 + la_r;
    const bool bValid = (bRowG < N);
    const long long brow_base = (long long)bRowG * ldb;

    float acc[4][4] = {};

    for (int k0 = 0; k0 < K; k0 += BK) {
        float4 av = *(const float4*)(A + arow_base + k0 + la_k);
        float4 bv = make_float4(0.f, 0.f, 0.f, 0.f);
        if (bValid) bv = *(const float4*)(Bm + brow_base + k0 + la_k);

        As[la_k + 0][la_r] = av.x; As[la_k + 1][la_r] = av.y;
        As[la_k + 2][la_r] = av.z; As[la_k + 3][la_r] = av.w;
        Bs[la_k + 0][la_r] = bv.x; Bs[la_k + 1][la_r] = bv.y;
        Bs[la_k + 2][la_r] = bv.z; Bs[la_k + 3][la_r] = bv.w;
        __syncthreads();

        #pragma unroll
        for (int kk = 0; kk < BK; ++kk) {
            float af[4], bf[4];
            #pragma unroll
            for (int i = 0; i < 4; ++i) af[i] = As[kk][ty * 4 + i];
            #pragma unroll
            for (int j = 0; j < 4; ++j) bf[j] = Bs[kk][tx * 4 + j];
            #pragma unroll
            for (int i = 0; i < 4; ++i)
                #pragma unroll
                for (int j = 0; j < 4; ++j)
                    acc[i][j] = fmaf(af[i], bf[j], acc[i][j]);
        }
        __syncthreads();
    }

    #pragma unroll
    for (int i = 0; i < 4; ++i) {
        const int row = brow0 + ty * 4 + i;
        #pragma unroll
        for (int j = 0; j < 4; ++j) {
            const int col = bcol0 + tx * 4 + j;
            if (col < N) {
                float v = acc[i][j];
                if (bias) v += bias[col];
                C[(long long)row * ldc + col] = v;
            }
        }
    }
}

// ---------------------------------------------------------------------------
// f32 -> bf16 conversion with optional column slice + zero row padding
// ---------------------------------------------------------------------------
__global__ void conv2bf(const float* __restrict__ src, unsigned short* __restrict__ dst,
                        int rows, int rowsPad, int cols, int srcld, int srccol0)
{
    int i = blockIdx.x * blockDim.x + threadIdx.x;
    int c4n = cols >> 2;
    if (i >= rowsPad * c4n) return;
    int r = i / c4n, c4 = i % c4n;
    ushort4 o;
    if (r < rows) {
        float4 v = *(const float4*)(src + (long long)r * srcld + srccol0 + c4 * 4);
        o.x = f2b(v.x); o.y = f2b(v.y); o.z = f2b(v.z); o.w = f2b(v.w);
    } else {
        o = make_ushort4(0, 0, 0, 0);
    }
    *(ushort4*)(dst + (long long)r * cols + c4 * 4) = o;
}

// ---------------------------------------------------------------------------
// prep: gather indices + combined bias
// idxEmb ordered for gates rows r = t*B + b (gates layout [T,B,...])
// idxLog: blocked-hs row index, ar = slot*16384 + b  (slot = t+1)
// ---------------------------------------------------------------------------
__global__ void prep_kernel(const int* __restrict__ labels,
                            const float* __restrict__ b_ih,
                            const float* __restrict__ b_hh,
                            int* __restrict__ idxEmb,
                            int* __restrict__ idxLog,
                            float* __restrict__ bsum)
{
    int r = blockIdx.x * blockDim.x + threadIdx.x;
    if (r < B_ * T_) {
        {   // embedding gather: r = t*B + b
            int t = r >> 8, b = r & (B_ - 1);
            int tsrc = (t == 0) ? (T_ - 1) : (t - 1);
            idxEmb[r] = labels[b * T_ + tsrc];
        }
        {   // logits gather: r = b*T + t  -> hs slot t+1 (blocked)
            int b = r / T_, t = r % T_;
            idxLog[r] = (t + 1) * 16384 + b;
        }
    }
    if (r < G4_) bsum[r] = b_ih[r] + b_hh[r];
}

extern "C" void kernel_launch(void* const* d_in, const int* in_sizes, int n_in,
                              void* d_out, int out_size, void* d_ws, size_t ws_size,
                              hipStream_t stream)
{
    const float* X      = (const float*)d_in[0];
    const int*   labels = (const int*)  d_in[1];
    const float* W_f    = (const float*)d_in[2];
    const float* b_f    = (const float*)d_in[3];
    const float* emb    = (const float*)d_in[4];
    const float* W_ih   = (const float*)d_in[5];
    const float* W_hh   = (const float*)d_in[6];
    const float* b_ih   = (const float*)d_in[7];
    const float* b_hh   = (const float*)d_in[8];
    const float* W_out  = (const float*)d_in[9];
    const float* b_out  = (const float*)d_in[10];
    float* out = (float*)d_out;
    (void)in_sizes; (void)n_in; (void)out_size; (void)ws_size;

    char* ws = (char*)d_ws;
    size_t off = 0;
    auto alloc = [&](size_t bytes) {
        void* p = ws + off;
        off += (bytes + 255) & ~(size_t)255;
        return p;
    };
    unsigned short* emb_bf  = (unsigned short*)alloc((size_t)(V_ + 1) * E_ * 2);
    unsigned short* WihE_bf = (unsigned short*)alloc((size_t)G4_ * E_ * 2);
    unsigned short* Whh_bf  = (unsigned short*)alloc((size_t)G4_ * H_ * 2);
    unsigned short* Wout_bf = (unsigned short*)alloc((size_t)5120 * H_ * 2);
    unsigned short* hs_bf   = (unsigned short*)alloc((size_t)(T_ + 1) * 262144 * 2);
    float* features = (float*)alloc(B_ * E_ * 4);
    float* bsum     = (float*)alloc(G4_ * 4);
    int*   idxEmb   = (int*)  alloc(B_ * T_ * 4);
    int*   idxLog   = (int*)  alloc(B_ * T_ * 4);
    unsigned int* done = (unsigned int*)alloc(256 * 4);

    // d_out reuse: gates [T,B,1024,4] at the front (fully consumed by the
    // recurrence before the logits GEMM overwrites d_out); baseMat in tail.
    float* gates   = out;
    float* baseMat = out + (size_t)B_ * T_ * G4_;   // 41.94M + 1.05M < 51.2M

    hipMemsetAsync(done, 0, 256 * 4, stream);       // step flags = 0

    prep_kernel<<<(B_ * T_ + 255) / 256, 256, 0, stream>>>(
        labels, b_ih, b_hh, idxEmb, idxLog, bsum);

    {
        int n;
        n = (V_ + 1) * E_ / 4;
        conv2bf<<<(n + 255) / 256, 256, 0, stream>>>(emb, emb_bf, V_ + 1, V_ + 1, E_, E_, 0);
        n = G4_ * E_ / 4;
        conv2bf<<<(n + 255) / 256, 256, 0, stream>>>(W_ih, WihE_bf, G4_, G4_, E_, 2 * E_, E_);
        n = G4_ * H_ / 4;
        conv2bf<<<(n + 255) / 256, 256, 0, stream>>>(W_hh, Whh_bf, G4_, G4_, H_, H_, 0);
        n = 5120 * H_ / 4;
        conv2bf<<<(n + 255) / 256, 256, 0, stream>>>(W_out, Wout_bf, V_, 5120, H_, H_, 0);
    }

    dim3 thr(16, 16);

    // features = X @ W_f^T + b_f            [256,512] K=2048 (fp32)
    gemm_bt<<<dim3(E_ / 64, B_ / 64), thr, 0, stream>>>(
        X, IN_, W_f, IN_, b_f, features, E_, E_, IN_);

    // base = features @ W_ih[:, :E]^T + (b_ih + b_hh)   [256,4096] K=512 (fp32)
    gemm_bt<<<dim3(G4_ / 64, B_ / 64), thr, 0, stream>>>(
        features, E_, W_ih, 2 * E_, bsum, baseMat, G4_, G4_, E_);

    // gates[t,b,:] = gather(emb_bf) @ WihE^T + base[b], PERMUTED cols
    gemm_mfma<<<dim3(G4_ / 128, (B_ * T_) / 128), 256, 0, stream>>>(
        emb_bf, E_, 0, idxEmb, WihE_bf, E_, nullptr,
        baseMat, B_ - 1, G4_, gates, G4_, 1, G4_, E_);

    // ---- persistent recurrence (all 40 steps, one plain launch) ----
    {
        hipFuncSetAttribute((const void*)recur_persist,
                            hipFuncAttributeMaxDynamicSharedMemorySize, 131072);
        recur_persist<<<256, 256, 131072, stream>>>(hs_bf, Whh_bf, gates, done);
    }

    // logits = gather(hs_bf blocked) @ W_out^T + b_out   [10240,5000] K=1024
    gemm_mfma<<<dim3(5120 / 128, (B_ * T_) / 128), 256, 0, stream>>>(
        hs_bf, 16, 1, idxLog, Wout_bf, H_, b_out,
        nullptr, 0, 0, out, V_, 0, V_, H_);
}

// Round 8
// 889.617 us; speedup vs baseline: 1.3920x; 1.2277x over previous
//
#include <hip/hip_runtime.h>
#include <hip/hip_bf16.h>
#include <math.h>

#define B_  256
#define T_  40
#define IN_ 2048
#define E_  512
#define H_  1024
#define V_  5000
#define G4_ 4096   // 4*H

typedef __bf16 bf16x8 __attribute__((ext_vector_type(8)));
typedef float  f32x4  __attribute__((ext_vector_type(4)));
typedef unsigned int u32x4 __attribute__((ext_vector_type(4)));

__device__ __forceinline__ float sigm_f(float x) { return 1.0f / (1.0f + __expf(-x)); }
__device__ __forceinline__ float tanh_f(float x) { return 1.0f - 2.0f / (1.0f + __expf(2.0f * x)); }

__device__ __forceinline__ unsigned short f2b(float x) {
    __hip_bfloat16 h = __float2bfloat16(x);
    return *reinterpret_cast<unsigned short*>(&h);
}

#define GLOAD_LDS(g, l) __builtin_amdgcn_global_load_lds(                     \
    (const __attribute__((address_space(1))) unsigned int*)(g),               \
    (__attribute__((address_space(3))) unsigned int*)(l), 16, 0, 0)

// LLC-coherent (cross-XCD) loads/stores
__device__ __forceinline__ void llc_load16(u32x4* dst, const unsigned short* p) {
    asm volatile("global_load_dwordx4 %0, %1, off sc0 sc1" : "=v"(*dst) : "v"(p));
}
__device__ __forceinline__ void llc_store16(unsigned short* p, u32x4 v) {
    asm volatile("global_store_dwordx4 %0, %1, off sc0 sc1" :: "v"(p), "v"(v) : "memory");
}
__device__ __forceinline__ void llc_store4(unsigned int* p, unsigned int v) {
    asm volatile("global_store_dword %0, %1, off sc0 sc1" :: "v"(p), "v"(v) : "memory");
}
// poll load: waitcnt INSIDE the asm (compiler doesn't track asm loads)
__device__ __forceinline__ unsigned long long llc_load8_wait(const unsigned int* p) {
    unsigned long long v;
    asm volatile("global_load_dwordx2 %0, %1, off sc0 sc1\n\ts_waitcnt vmcnt(0)"
                 : "=v"(v) : "v"(p) : "memory");
    return v;
}
#define VM_WAIT(n) do {                                                       \
    asm volatile("s_waitcnt vmcnt(" #n ")" ::: "memory");                     \
    __builtin_amdgcn_sched_barrier(0);                                        \
} while (0)

// ---------------------------------------------------------------------------
// bf16 MFMA GEMM: C[M,N](f32) = gather(A) @ B^T + bias[N]
//                 + addMat[(row & rowMask)*addStride + col]
// aBlocked: A stored as [kblk][256 rows][16] blocks (hs layout).
// permuteC: store col' = (col%1024)*4 + col/1024  (gates [B][1024][4] layout).
// 128x128 tile, BK=32, 256 thr = 4 waves, 16x16x32 MFMA.
// ---------------------------------------------------------------------------
__global__ __launch_bounds__(256) void gemm_mfma(
    const unsigned short* __restrict__ A, int lda, int aBlocked,
    const int* __restrict__ gidx,
    const unsigned short* __restrict__ Bm, int ldb,
    const float* __restrict__ bias,
    const float* __restrict__ addMat, int rowMask, long long addStride,
    float* __restrict__ C, int ldc, int permuteC, int N, int K)
{
    __shared__ unsigned short As[128 * 32];
    __shared__ unsigned short Bs[128 * 32];

    const int tid  = threadIdx.x;
    const int wave = tid >> 6, lane = tid & 63;
    const int brow0 = blockIdx.y * 128, bcol0 = blockIdx.x * 128;
    const int wrow0 = (wave >> 1) * 64, wcol0 = (wave & 1) * 64;

    const int srow = lane >> 2;
    const int scol = (lane & 3) * 8;
    const size_t kstep = aBlocked ? 256 : 1;
    const unsigned short* pA[2];
    const unsigned short* pB[2];
    unsigned short* lA[2];
    unsigned short* lB[2];
    #pragma unroll
    for (int i = 0; i < 2; ++i) {
        int seg = wave * 2 + i;
        int row = seg * 16 + srow;
        long long ar = gidx ? (long long)gidx[brow0 + row] : (long long)(brow0 + row);
        if (aBlocked)
            pA[i] = A + ((size_t)ar << 4) + ((size_t)(scol >> 4) << 12) + (scol & 8);
        else
            pA[i] = A + (size_t)ar * lda + scol;
        pB[i] = Bm + (long long)(bcol0 + row) * ldb + scol;
        lA[i] = &As[seg * 16 * 32];
        lB[i] = &Bs[seg * 16 * 32];
    }

    f32x4 acc[4][4] = {};
    const int foff = (lane & 15) * 32 + (lane >> 4) * 8;

    for (int k0 = 0; k0 < K; k0 += 32) {
        GLOAD_LDS(pA[0] + (size_t)k0 * kstep, lA[0]);
        GLOAD_LDS(pA[1] + (size_t)k0 * kstep, lA[1]);
        GLOAD_LDS(pB[0] + k0, lB[0]);
        GLOAD_LDS(pB[1] + k0, lB[1]);
        __syncthreads();

        bf16x8 a[4], b[4];
        #pragma unroll
        for (int m = 0; m < 4; ++m)
            a[m] = *(const bf16x8*)&As[(wrow0 + m * 16) * 32 + foff];
        #pragma unroll
        for (int n = 0; n < 4; ++n)
            b[n] = *(const bf16x8*)&Bs[(wcol0 + n * 16) * 32 + foff];
        #pragma unroll
        for (int m = 0; m < 4; ++m)
            #pragma unroll
            for (int n = 0; n < 4; ++n)
                acc[m][n] = __builtin_amdgcn_mfma_f32_16x16x32_bf16(
                    a[m], b[n], acc[m][n], 0, 0, 0);
        __syncthreads();
    }

    #pragma unroll
    for (int m = 0; m < 4; ++m) {
        #pragma unroll
        for (int j = 0; j < 4; ++j) {
            int row = brow0 + wrow0 + m * 16 + (lane >> 4) * 4 + j;
            const float* addRow = addMat
                ? addMat + (long long)(row & rowMask) * addStride : nullptr;
            #pragma unroll
            for (int n = 0; n < 4; ++n) {
                int col = bcol0 + wcol0 + n * 16 + (lane & 15);
                if (col < N) {
                    float v = acc[m][n][j];
                    if (bias)   v += bias[col];
                    if (addRow) v += addRow[col];
                    int cidx = permuteC ? (((col & 1023) << 2) | (col >> 10)) : col;
                    C[(long long)row * ldc + cidx] = v;
                }
            }
        }
    }
}

// ---------------------------------------------------------------------------
// Persistent LSTM recurrence v3 (plain launch, 256 WGs x 256 thr).
// WG (mb = bid>>6, hb = bid&63): batch rows mb*64..+64, h-cols hb*16..+16.
// W_hh slice [64 gate-rows x 1024] bf16 LDS-resident (128 KB, XOR-swizzled).
// h BLOCKED: slot t = [64 kblk][256 row][16]; per-WG output tile = one 2 KB
// span, stored as 128 coalesced 16B sc0sc1 stores via 3 KB LDS stage.
// gates PERMUTED [T][B][1024][4] -> one float4 per row = i/f/g/o quad.
// SYNC (v3): no atomics. Producer waves 0/1 each publish a per-wave flag
// (plain sc0sc1 dword) after their own vmcnt(0) store-ack. Consumers detect
// with a 64-lane parallel poll (lane l reads WG l's 8B flag pair) + __all.
// No post-store barrier; each wave polls and proceeds independently.
// ---------------------------------------------------------------------------
__global__ __launch_bounds__(256) void recur_persist(
    unsigned short* __restrict__ hs,          // slots 1..40, each 262144 elems
    const unsigned short* __restrict__ Whh,   // [4096,1024] bf16
    const float* __restrict__ gates,          // [T,B,1024,4] f32 (permuted)
    unsigned int* __restrict__ flags)         // [(T+1)][256][2], zeroed
{
    extern __shared__ unsigned short lds[];   // [64][1024] bf16 = 128 KB
    __shared__ unsigned short hstage[64][24]; // store-coalescing scratch

    const int tid = threadIdx.x;
    const int w = tid >> 6, lane = tid & 63;
    const int mb = blockIdx.x >> 6;           // 0..3
    const int hb = blockIdx.x & 63;           // 0..63
    const int r16 = lane & 15, g4 = lane >> 4;
    const int sw7 = r16 & 7;
    const size_t SLOT = 262144;               // 64*256*16

    // ---- stage W_hh slice into LDS once (wave w = gate q) ----
    {
        const int q = w;
        for (int r = 0; r < 16; ++r) {
            const int g = q * 16 + r;
            const unsigned short* rowsrc =
                Whh + ((size_t)q * 1024 + hb * 16 + r) * H_;
            #pragma unroll
            for (int half = 0; half < 2; ++half) {
                int gran = (half * 64 + lane) ^ (g & 7);
                GLOAD_LDS(rowsrc + gran * 8, &lds[g * 1024 + half * 512]);
            }
        }
    }
    asm volatile("s_waitcnt vmcnt(0)" ::: "memory");
    __syncthreads();

    // per-lane coordinates
    const int arow = mb * 64 + w * 16 + r16;         // A row (blocked layout)
    const size_t abase = ((size_t)arow << 4) + ((g4 >> 1) << 12) + ((g4 & 1) << 3);
    const int orow0 = mb * 64 + w * 16 + g4 * 4;     // output rows +j
    const int hc    = hb * 16 + r16;                 // h column
    const int lrow0 = w * 16 + g4 * 4;               // local tile row

    int qbase[4];
    #pragma unroll
    for (int q = 0; q < 4; ++q) qbase[q] = (q * 16 + r16) << 11;

    float cc[4];

    // store path: stage tile in LDS, 128 x 16B coalesced sc0sc1 stores,
    // per-wave vmcnt(0) ack, then per-wave flag (lane 0). No barrier after.
    #define STORE_H(T1, HV)                                                   \
    {                                                                         \
        _Pragma("unroll")                                                     \
        for (int j = 0; j < 4; ++j) hstage[lrow0 + j][r16] = HV[j];           \
        __syncthreads();                                                      \
        if (tid < 128) {                                                      \
            u32x4 v = *(const u32x4*)&hstage[tid >> 1][(tid & 1) * 8];        \
            unsigned short* dst = hs + (size_t)(T1) * SLOT +                  \
                (((size_t)hb * 256 + mb * 64) << 4) + (size_t)tid * 8;        \
            llc_store16(dst, v);                                              \
            asm volatile("s_waitcnt vmcnt(0)" ::: "memory");                  \
            if (lane == 0)                                                    \
                llc_store4(flags + (((T1) << 8) + (mb << 6) + hb) * 2 + w, 1u); \
        }                                                                     \
    }

    // ---- step 0: h0 = 0 -> gates only ----
    {
        unsigned short hv[4];
        #pragma unroll
        for (int j = 0; j < 4; ++j) {
            f32x4 gq = *(const f32x4*)(gates + ((size_t)(orow0 + j) << 12) + (hc << 2));
            float c2 = sigm_f(gq[0]) * tanh_f(gq[2]);
            cc[j] = c2;
            hv[j] = f2b(sigm_f(gq[3]) * tanh_f(c2));
        }
        STORE_H(1, hv)
    }

    // ---- steps 1..39 ----
    for (int t = 1; t < T_; ++t) {
        // gates for this step (independent of h -> issued before the poll)
        f32x4 gq[4];
        #pragma unroll
        for (int j = 0; j < 4; ++j)
            gq[j] = *(const f32x4*)(gates +
                ((size_t)(t * B_ + orow0 + j) << 12) + (hc << 2));

        // 64-lane parallel poll: lane l watches producer WG (mb, l)'s 2 flags
        {
            const unsigned int* fp =
                flags + (((size_t)t << 8) + (mb << 6) + lane) * 2;
            for (;;) {
                unsigned long long fv = llc_load8_wait(fp);
                if (__all(fv == 0x0000000100000001ULL)) break;
                __builtin_amdgcn_s_sleep(1);
            }
        }
        __builtin_amdgcn_sched_barrier(0);

        const unsigned short* hp = hs + (size_t)t * SLOT + abase;

        u32x4 a0[8], a1[8];
        #pragma unroll
        for (int u = 0; u < 8; ++u) llc_load16(&a0[u], hp + (size_t)u * 8192);
        #pragma unroll
        for (int u = 0; u < 8; ++u) llc_load16(&a1[u], hp + (size_t)(8 + u) * 8192);

        f32x4 acc[4] = {};

#define DO_CHUNK(BUF, KSB)                                                    \
        _Pragma("unroll")                                                     \
        for (int u = 0; u < 8; ++u) {                                         \
            bf16x8 a8 = __builtin_bit_cast(bf16x8, BUF[u]);                   \
            _Pragma("unroll")                                                 \
            for (int q = 0; q < 4; ++q) {                                     \
                int off = qbase[q] + (((((KSB) + u) * 4 + g4) ^ sw7) << 4);   \
                bf16x8 b8 = *(const bf16x8*)((const char*)lds + off);         \
                acc[q] = __builtin_amdgcn_mfma_f32_16x16x32_bf16(             \
                    a8, b8, acc[q], 0, 0, 0);                                 \
            }                                                                 \
        }

        VM_WAIT(8);
        DO_CHUNK(a0, 0)
        #pragma unroll
        for (int u = 0; u < 8; ++u) llc_load16(&a0[u], hp + (size_t)(16 + u) * 8192);
        VM_WAIT(8);
        DO_CHUNK(a1, 8)
        #pragma unroll
        for (int u = 0; u < 8; ++u) llc_load16(&a1[u], hp + (size_t)(24 + u) * 8192);
        VM_WAIT(8);
        DO_CHUNK(a0, 16)
        VM_WAIT(0);
        DO_CHUNK(a1, 24)
#undef DO_CHUNK

        // ---- fused cell ----
        unsigned short hv[4];
        #pragma unroll
        for (int j = 0; j < 4; ++j) {
            float gi = acc[0][j] + gq[j][0];
            float gf = acc[1][j] + gq[j][1];
            float gg = acc[2][j] + gq[j][2];
            float go = acc[3][j] + gq[j][3];
            float c2 = sigm_f(gf) * cc[j] + sigm_f(gi) * tanh_f(gg);
            cc[j] = c2;
            hv[j] = f2b(sigm_f(go) * tanh_f(c2));
        }
        STORE_H(t + 1, hv)
    }
    #undef STORE_H
}

// ---------------------------------------------------------------------------
// fp32 tiled GEMM (two small GEMMs): C = A @ B^T + bias
// ---------------------------------------------------------------------------
__global__ __launch_bounds__(256) void gemm_bt(
    const float* __restrict__ A, int lda,
    const float* __restrict__ Bm, int ldb,
    const float* __restrict__ bias,
    float* __restrict__ C, int ldc, int N, int K)
{
    const int BK = 16;
    __shared__ float As[BK][64];
    __shared__ float Bs[BK][64];

    const int tx = threadIdx.x, ty = threadIdx.y;
    const int tid = ty * 16 + tx;
    const int brow0 = blockIdx.y * 64;
    const int bcol0 = blockIdx.x * 64;

    const int e0   = tid * 4;
    const int la_r = e0 / BK;
    const int la_k = e0 % BK;

    const long long arow_base = (long long)(brow0 + la_r) * lda;
    const int bRowG = bcol0 + la_r;
    const bool bValid = (bRowG < N);
    const long long brow_base = (long long)bRowG * ldb;

    float acc[4][4] = {};

    for (int k0 = 0; k0 < K; k0 += BK) {
        float4 av = *(const float4*)(A + arow_base + k0 + la_k);
        float4 bv = make_float4(0.f, 0.f, 0.f, 0.f);
        if (bValid) bv = *(const float4*)(Bm + brow_base + k0 + la_k);

        As[la_k + 0][la_r] = av.x; As[la_k + 1][la_r] = av.y;
        As[la_k + 2][la_r] = av.z; As[la_k + 3][la_r] = av.w;
        Bs[la_k + 0][la_r] = bv.x; Bs[la_k + 1][la_r] = bv.y;
        Bs[la_k + 2][la_r] = bv.z; Bs[la_k + 3][la_r] = bv.w;
        __syncthreads();

        #pragma unroll
        for (int kk = 0; kk < BK; ++kk) {
            float af[4], bf[4];
            #pragma unroll
            for (int i = 0; i < 4; ++i) af[i] = As[kk][ty * 4 + i];
            #pragma unroll
            for (int j = 0; j < 4; ++j) bf[j] = Bs[kk][tx * 4 + j];
            #pragma unroll
            for (int i = 0; i < 4; ++i)
                #pragma unroll
                for (int j = 0; j < 4; ++j)
                    acc[i][j] = fmaf(af[i], bf[j], acc[i][j]);
        }
        __syncthreads();
    }

    #pragma unroll
    for (int i = 0; i < 4; ++i) {
        const int row = brow0 + ty * 4 + i;
        #pragma unroll
        for (int j = 0; j < 4; ++j) {
            const int col = bcol0 + tx * 4 + j;
            if (col < N) {
                float v = acc[i][j];
                if (bias) v += bias[col];
                C[(long long)row * ldc + col] = v;
            }
        }
    }
}

// ---------------------------------------------------------------------------
// f32 -> bf16 conversion with optional column slice + zero row padding
// ---------------------------------------------------------------------------
__global__ void conv2bf(const float* __restrict__ src, unsigned short* __restrict__ dst,
                        int rows, int rowsPad, int cols, int srcld, int srccol0)
{
    int i = blockIdx.x * blockDim.x + threadIdx.x;
    int c4n = cols >> 2;
    if (i >= rowsPad * c4n) return;
    int r = i / c4n, c4 = i % c4n;
    ushort4 o;
    if (r < rows) {
        float4 v = *(const float4*)(src + (long long)r * srcld + srccol0 + c4 * 4);
        o.x = f2b(v.x); o.y = f2b(v.y); o.z = f2b(v.z); o.w = f2b(v.w);
    } else {
        o = make_ushort4(0, 0, 0, 0);
    }
    *(ushort4*)(dst + (long long)r * cols + c4 * 4) = o;
}

// ---------------------------------------------------------------------------
// prep: gather indices + combined bias
// idxEmb ordered for gates rows r = t*B + b (gates layout [T,B,...])
// idxLog: blocked-hs row index, ar = slot*16384 + b  (slot = t+1)
// ---------------------------------------------------------------------------
__global__ void prep_kernel(const int* __restrict__ labels,
                            const float* __restrict__ b_ih,
                            const float* __restrict__ b_hh,
                            int* __restrict__ idxEmb,
                            int* __restrict__ idxLog,
                            float* __restrict__ bsum)
{
    int r = blockIdx.x * blockDim.x + threadIdx.x;
    if (r < B_ * T_) {
        {   // embedding gather: r = t*B + b
            int t = r >> 8, b = r & (B_ - 1);
            int tsrc = (t == 0) ? (T_ - 1) : (t - 1);
            idxEmb[r] = labels[b * T_ + tsrc];
        }
        {   // logits gather: r = b*T + t  -> hs slot t+1 (blocked)
            int b = r / T_, t = r % T_;
            idxLog[r] = (t + 1) * 16384 + b;
        }
    }
    if (r < G4_) bsum[r] = b_ih[r] + b_hh[r];
}

extern "C" void kernel_launch(void* const* d_in, const int* in_sizes, int n_in,
                              void* d_out, int out_size, void* d_ws, size_t ws_size,
                              hipStream_t stream)
{
    const float* X      = (const float*)d_in[0];
    const int*   labels = (const int*)  d_in[1];
    const float* W_f    = (const float*)d_in[2];
    const float* b_f    = (const float*)d_in[3];
    const float* emb    = (const float*)d_in[4];
    const float* W_ih   = (const float*)d_in[5];
    const float* W_hh   = (const float*)d_in[6];
    const float* b_ih   = (const float*)d_in[7];
    const float* b_hh   = (const float*)d_in[8];
    const float* W_out  = (const float*)d_in[9];
    const float* b_out  = (const float*)d_in[10];
    float* out = (float*)d_out;
    (void)in_sizes; (void)n_in; (void)out_size; (void)ws_size;

    char* ws = (char*)d_ws;
    size_t off = 0;
    auto alloc = [&](size_t bytes) {
        void* p = ws + off;
        off += (bytes + 255) & ~(size_t)255;
        return p;
    };
    unsigned short* emb_bf  = (unsigned short*)alloc((size_t)(V_ + 1) * E_ * 2);
    unsigned short* WihE_bf = (unsigned short*)alloc((size_t)G4_ * E_ * 2);
    unsigned short* Whh_bf  = (unsigned short*)alloc((size_t)G4_ * H_ * 2);
    unsigned short* Wout_bf = (unsigned short*)alloc((size_t)5120 * H_ * 2);
    unsigned short* hs_bf   = (unsigned short*)alloc((size_t)(T_ + 1) * 262144 * 2);
    float* features = (float*)alloc(B_ * E_ * 4);
    float* bsum     = (float*)alloc(G4_ * 4);
    int*   idxEmb   = (int*)  alloc(B_ * T_ * 4);
    int*   idxLog   = (int*)  alloc(B_ * T_ * 4);
    unsigned int* flags = (unsigned int*)alloc((size_t)(T_ + 1) * 256 * 2 * 4);

    // d_out reuse: gates [T,B,1024,4] at the front (fully consumed by the
    // recurrence before the logits GEMM overwrites d_out); baseMat in tail.
    float* gates   = out;
    float* baseMat = out + (size_t)B_ * T_ * G4_;   // 41.94M + 1.05M < 51.2M

    hipMemsetAsync(flags, 0, (size_t)(T_ + 1) * 256 * 2 * 4, stream);

    prep_kernel<<<(B_ * T_ + 255) / 256, 256, 0, stream>>>(
        labels, b_ih, b_hh, idxEmb, idxLog, bsum);

    {
        int n;
        n = (V_ + 1) * E_ / 4;
        conv2bf<<<(n + 255) / 256, 256, 0, stream>>>(emb, emb_bf, V_ + 1, V_ + 1, E_, E_, 0);
        n = G4_ * E_ / 4;
        conv2bf<<<(n + 255) / 256, 256, 0, stream>>>(W_ih, WihE_bf, G4_, G4_, E_, 2 * E_, E_);
        n = G4_ * H_ / 4;
        conv2bf<<<(n + 255) / 256, 256, 0, stream>>>(W_hh, Whh_bf, G4_, G4_, H_, H_, 0);
        n = 5120 * H_ / 4;
        conv2bf<<<(n + 255) / 256, 256, 0, stream>>>(W_out, Wout_bf, V_, 5120, H_, H_, 0);
    }

    dim3 thr(16, 16);

    // features = X @ W_f^T + b_f            [256,512] K=2048 (fp32)
    gemm_bt<<<dim3(E_ / 64, B_ / 64), thr, 0, stream>>>(
        X, IN_, W_f, IN_, b_f, features, E_, E_, IN_);

    // base = features @ W_ih[:, :E]^T + (b_ih + b_hh)   [256,4096] K=512 (fp32)
    gemm_bt<<<dim3(G4_ / 64, B_ / 64), thr, 0, stream>>>(
        features, E_, W_ih, 2 * E_, bsum, baseMat, G4_, G4_, E_);

    // gates[t,b,:] = gather(emb_bf) @ WihE^T + base[b], PERMUTED cols
    gemm_mfma<<<dim3(G4_ / 128, (B_ * T_) / 128), 256, 0, stream>>>(
        emb_bf, E_, 0, idxEmb, WihE_bf, E_, nullptr,
        baseMat, B_ - 1, G4_, gates, G4_, 1, G4_, E_);

    // ---- persistent recurrence (all 40 steps, one plain launch) ----
    {
        hipFuncSetAttribute((const void*)recur_persist,
                            hipFuncAttributeMaxDynamicSharedMemorySize, 131072);
        recur_persist<<<256, 256, 131072, stream>>>(hs_bf, Whh_bf, gates, flags);
    }

    // logits = gather(hs_bf blocked) @ W_out^T + b_out   [10240,5000] K=1024
    gemm_mfma<<<dim3(5120 / 128, (B_ * T_) / 128), 256, 0, stream>>>(
        hs_bf, 16, 1, idxLog, Wout_bf, H_, b_out,
        nullptr, 0, 0, out, V_, 0, V_, H_);
}

// Round 9
// 875.431 us; speedup vs baseline: 1.4145x; 1.0162x over previous
//
#include <hip/hip_runtime.h>
#include <hip/hip_bf16.h>
#include <math.h>

#define B_  256
#define T_  40
#define IN_ 2048
#define E_  512
#define H_  1024
#define V_  5000
#define G4_ 4096   // 4*H

typedef __bf16 bf16x8 __attribute__((ext_vector_type(8)));
typedef float  f32x4  __attribute__((ext_vector_type(4)));
typedef unsigned int u32x4 __attribute__((ext_vector_type(4)));

__device__ __forceinline__ float sigm_f(float x) { return 1.0f / (1.0f + __expf(-x)); }
__device__ __forceinline__ float tanh_f(float x) { return 1.0f - 2.0f / (1.0f + __expf(2.0f * x)); }

__device__ __forceinline__ unsigned short f2b(float x) {
    __hip_bfloat16 h = __float2bfloat16(x);
    return *reinterpret_cast<unsigned short*>(&h);
}

#define GLOAD_LDS(g, l) __builtin_amdgcn_global_load_lds(                     \
    (const __attribute__((address_space(1))) unsigned int*)(g),               \
    (__attribute__((address_space(3))) unsigned int*)(l), 16, 0, 0)

// normal (L2-cached) 16B load, manual vmcnt accounting via VM_WAIT
__device__ __forceinline__ void l2_load16(u32x4* dst, const unsigned short* p) {
    asm volatile("global_load_dwordx4 %0, %1, off" : "=v"(*dst) : "v"(p));
}
// LLC-coherent (cross-XCD) stores + poll
__device__ __forceinline__ void llc_store16(unsigned short* p, u32x4 v) {
    asm volatile("global_store_dwordx4 %0, %1, off sc0 sc1" :: "v"(p), "v"(v) : "memory");
}
__device__ __forceinline__ void llc_store4(unsigned int* p, unsigned int v) {
    asm volatile("global_store_dword %0, %1, off sc0 sc1" :: "v"(p), "v"(v) : "memory");
}
// poll load: waitcnt INSIDE the asm (compiler doesn't track asm loads)
__device__ __forceinline__ unsigned long long llc_load8_wait(const unsigned int* p) {
    unsigned long long v;
    asm volatile("global_load_dwordx2 %0, %1, off sc0 sc1\n\ts_waitcnt vmcnt(0)"
                 : "=v"(v) : "v"(p) : "memory");
    return v;
}
#define VM_WAIT(n) do {                                                       \
    asm volatile("s_waitcnt vmcnt(" #n ")" ::: "memory");                     \
    __builtin_amdgcn_sched_barrier(0);                                        \
} while (0)

// ---------------------------------------------------------------------------
// bf16 MFMA GEMM, 2-phase pipelined (T3 minimum recipe):
//   STAGE(next tile) -> ds_read(cur) -> MFMA -> vmcnt(0)+barrier -> swap.
// C[M,N](f32) = gather(A) @ B^T + bias[N] + addMat[(row&rowMask)*addStride+col]
// aBlocked: A stored as [kblk][256 rows][16] blocks (hs layout).
// permuteC: store col' = (col%1024)*4 + col/1024  (gates [B][1024][4] layout).
// 128x128 tile, BK=32, 256 thr = 4 waves, 16x16x32 MFMA. LDS 32 KB (2 buf).
// ---------------------------------------------------------------------------
__global__ __launch_bounds__(256) void gemm_mfma(
    const unsigned short* __restrict__ A, int lda, int aBlocked,
    const int* __restrict__ gidx,
    const unsigned short* __restrict__ Bm, int ldb,
    const float* __restrict__ bias,
    const float* __restrict__ addMat, int rowMask, long long addStride,
    float* __restrict__ C, int ldc, int permuteC, int N, int K)
{
    __shared__ unsigned short As[2][128 * 32];
    __shared__ unsigned short Bs[2][128 * 32];

    const int tid  = threadIdx.x;
    const int wave = tid >> 6, lane = tid & 63;
    const int brow0 = blockIdx.y * 128, bcol0 = blockIdx.x * 128;
    const int wrow0 = (wave >> 1) * 64, wcol0 = (wave & 1) * 64;

    const int srow = lane >> 2;
    const int scol = (lane & 3) * 8;
    const size_t kstep = aBlocked ? 256 : 1;
    const unsigned short* pA[2];
    const unsigned short* pB[2];
    unsigned short* lA[2];
    unsigned short* lB[2];
    #pragma unroll
    for (int i = 0; i < 2; ++i) {
        int seg = wave * 2 + i;
        int row = seg * 16 + srow;
        long long ar = gidx ? (long long)gidx[brow0 + row] : (long long)(brow0 + row);
        if (aBlocked)
            pA[i] = A + ((size_t)ar << 4) + ((size_t)(scol >> 4) << 12) + (scol & 8);
        else
            pA[i] = A + (size_t)ar * lda + scol;
        pB[i] = Bm + (long long)(bcol0 + row) * ldb + scol;
        lA[i] = &As[0][seg * 16 * 32];
        lB[i] = &Bs[0][seg * 16 * 32];
    }

    f32x4 acc[4][4] = {};
    const int foff = (lane & 15) * 32 + (lane >> 4) * 8;

    #define STAGE(buf, k0)                                                    \
        GLOAD_LDS(pA[0] + (size_t)(k0) * kstep, lA[0] + (buf) * 4096);        \
        GLOAD_LDS(pA[1] + (size_t)(k0) * kstep, lA[1] + (buf) * 4096);        \
        GLOAD_LDS(pB[0] + (k0), lB[0] + (buf) * 4096);                        \
        GLOAD_LDS(pB[1] + (k0), lB[1] + (buf) * 4096);

    STAGE(0, 0)
    asm volatile("s_waitcnt vmcnt(0)" ::: "memory");
    __syncthreads();

    int cur = 0;
    for (int k0 = 0; k0 < K; k0 += 32) {
        if (k0 + 32 < K) { STAGE(cur ^ 1, k0 + 32) }

        bf16x8 a[4], b[4];
        #pragma unroll
        for (int m = 0; m < 4; ++m)
            a[m] = *(const bf16x8*)&As[cur][(wrow0 + m * 16) * 32 + foff];
        #pragma unroll
        for (int n = 0; n < 4; ++n)
            b[n] = *(const bf16x8*)&Bs[cur][(wcol0 + n * 16) * 32 + foff];
        #pragma unroll
        for (int m = 0; m < 4; ++m)
            #pragma unroll
            for (int n = 0; n < 4; ++n)
                acc[m][n] = __builtin_amdgcn_mfma_f32_16x16x32_bf16(
                    a[m], b[n], acc[m][n], 0, 0, 0);

        asm volatile("s_waitcnt vmcnt(0)" ::: "memory");
        __syncthreads();
        cur ^= 1;
    }
    #undef STAGE

    #pragma unroll
    for (int m = 0; m < 4; ++m) {
        #pragma unroll
        for (int j = 0; j < 4; ++j) {
            int row = brow0 + wrow0 + m * 16 + (lane >> 4) * 4 + j;
            const float* addRow = addMat
                ? addMat + (long long)(row & rowMask) * addStride : nullptr;
            #pragma unroll
            for (int n = 0; n < 4; ++n) {
                int col = bcol0 + wcol0 + n * 16 + (lane & 15);
                if (col < N) {
                    float v = acc[m][n][j];
                    if (bias)   v += bias[col];
                    if (addRow) v += addRow[col];
                    int cidx = permuteC ? (((col & 1023) << 2) | (col >> 10)) : col;
                    C[(long long)row * ldc + cidx] = v;
                }
            }
        }
    }
}

// ---------------------------------------------------------------------------
// Persistent LSTM recurrence v4 (plain launch, 256 WGs x 256 thr).
// WG (mb = bid>>6, hb = bid&63): batch rows mb*64..+64, h-cols hb*16..+16.
// W_hh slice [64 gate-rows x 1024] bf16 LDS-resident (128 KB, XOR-swizzled).
// h BLOCKED: slot t = [64 kblk][256 row][16]; per-WG output tile = one 2 KB
// span, stored as 128 coalesced 16B sc0sc1 stores via 3 KB LDS stage.
// gates PERMUTED [T][B][1024][4] -> one float4 per row = i/f/g/o quad.
// SYNC: per-wave flags (plain sc0sc1 dword after per-wave vmcnt(0) ack);
// consumers detect via 64-lane parallel poll + __all.
// v4: h LOADS are NORMAL (L2-cached). Safe because: lines for slot t can
// only enter an L2 via (a) same-mb peers reading after the same flag
// condition (correct data) or (b) prior deterministic replays (identical
// values); producer sc0sc1 stores put truth at the LLC, which normal misses
// fetch. This converts ~7/8 of the 32 MB/step read amplification into
// same-XCD L2 hits (8 same-mb readers per XCD read the same 128 KB slice).
// ---------------------------------------------------------------------------
__global__ __launch_bounds__(256) void recur_persist(
    unsigned short* __restrict__ hs,          // slots 1..40, each 262144 elems
    const unsigned short* __restrict__ Whh,   // [4096,1024] bf16
    const float* __restrict__ gates,          // [T,B,1024,4] f32 (permuted)
    unsigned int* __restrict__ flags)         // [(T+1)][256][2], zeroed
{
    extern __shared__ unsigned short lds[];   // [64][1024] bf16 = 128 KB
    __shared__ unsigned short hstage[64][24]; // store-coalescing scratch

    const int tid = threadIdx.x;
    const int w = tid >> 6, lane = tid & 63;
    const int mb = blockIdx.x >> 6;           // 0..3
    const int hb = blockIdx.x & 63;           // 0..63
    const int r16 = lane & 15, g4 = lane >> 4;
    const int sw7 = r16 & 7;
    const size_t SLOT = 262144;               // 64*256*16

    // ---- stage W_hh slice into LDS once (wave w = gate q) ----
    {
        const int q = w;
        for (int r = 0; r < 16; ++r) {
            const int g = q * 16 + r;
            const unsigned short* rowsrc =
                Whh + ((size_t)q * 1024 + hb * 16 + r) * H_;
            #pragma unroll
            for (int half = 0; half < 2; ++half) {
                int gran = (half * 64 + lane) ^ (g & 7);
                GLOAD_LDS(rowsrc + gran * 8, &lds[g * 1024 + half * 512]);
            }
        }
    }
    asm volatile("s_waitcnt vmcnt(0)" ::: "memory");
    __syncthreads();

    // per-lane coordinates
    const int arow = mb * 64 + w * 16 + r16;         // A row (blocked layout)
    const size_t abase = ((size_t)arow << 4) + ((g4 >> 1) << 12) + ((g4 & 1) << 3);
    const int orow0 = mb * 64 + w * 16 + g4 * 4;     // output rows +j
    const int hc    = hb * 16 + r16;                 // h column
    const int lrow0 = w * 16 + g4 * 4;               // local tile row

    int qbase[4];
    #pragma unroll
    for (int q = 0; q < 4; ++q) qbase[q] = (q * 16 + r16) << 11;

    float cc[4];

    // store path: stage tile in LDS, 128 x 16B coalesced sc0sc1 stores,
    // per-wave vmcnt(0) ack, then per-wave flag (lane 0). No barrier after.
    #define STORE_H(T1, HV)                                                   \
    {                                                                         \
        _Pragma("unroll")                                                     \
        for (int j = 0; j < 4; ++j) hstage[lrow0 + j][r16] = HV[j];           \
        __syncthreads();                                                      \
        if (tid < 128) {                                                      \
            u32x4 v = *(const u32x4*)&hstage[tid >> 1][(tid & 1) * 8];        \
            unsigned short* dst = hs + (size_t)(T1) * SLOT +                  \
                (((size_t)hb * 256 + mb * 64) << 4) + (size_t)tid * 8;        \
            llc_store16(dst, v);                                              \
            asm volatile("s_waitcnt vmcnt(0)" ::: "memory");                  \
            if (lane == 0)                                                    \
                llc_store4(flags + (((T1) << 8) + (mb << 6) + hb) * 2 + w, 1u); \
        }                                                                     \
    }

    // ---- step 0: h0 = 0 -> gates only ----
    {
        unsigned short hv[4];
        #pragma unroll
        for (int j = 0; j < 4; ++j) {
            f32x4 gq = *(const f32x4*)(gates + ((size_t)(orow0 + j) << 12) + (hc << 2));
            float c2 = sigm_f(gq[0]) * tanh_f(gq[2]);
            cc[j] = c2;
            hv[j] = f2b(sigm_f(gq[3]) * tanh_f(c2));
        }
        STORE_H(1, hv)
    }

    // ---- steps 1..39 ----
    for (int t = 1; t < T_; ++t) {
        // gates for this step (independent of h -> issued before the poll)
        f32x4 gq[4];
        #pragma unroll
        for (int j = 0; j < 4; ++j)
            gq[j] = *(const f32x4*)(gates +
                ((size_t)(t * B_ + orow0 + j) << 12) + (hc << 2));

        // 64-lane parallel poll: lane l watches producer WG (mb, l)'s 2 flags
        {
            const unsigned int* fp =
                flags + (((size_t)t << 8) + (mb << 6) + lane) * 2;
            for (;;) {
                unsigned long long fv = llc_load8_wait(fp);
                if (__all(fv == 0x0000000100000001ULL)) break;
                __builtin_amdgcn_s_sleep(1);
            }
        }
        __builtin_amdgcn_sched_barrier(0);

        const unsigned short* hp = hs + (size_t)t * SLOT + abase;

        u32x4 a0[8], a1[8];
        #pragma unroll
        for (int u = 0; u < 8; ++u) l2_load16(&a0[u], hp + (size_t)u * 8192);
        #pragma unroll
        for (int u = 0; u < 8; ++u) l2_load16(&a1[u], hp + (size_t)(8 + u) * 8192);

        f32x4 acc[4] = {};

#define DO_CHUNK(BUF, KSB)                                                    \
        _Pragma("unroll")                                                     \
        for (int u = 0; u < 8; ++u) {                                         \
            bf16x8 a8 = __builtin_bit_cast(bf16x8, BUF[u]);                   \
            _Pragma("unroll")                                                 \
            for (int q = 0; q < 4; ++q) {                                     \
                int off = qbase[q] + (((((KSB) + u) * 4 + g4) ^ sw7) << 4);   \
                bf16x8 b8 = *(const bf16x8*)((const char*)lds + off);         \
                acc[q] = __builtin_amdgcn_mfma_f32_16x16x32_bf16(             \
                    a8, b8, acc[q], 0, 0, 0);                                 \
            }                                                                 \
        }

        VM_WAIT(8);
        DO_CHUNK(a0, 0)
        #pragma unroll
        for (int u = 0; u < 8; ++u) l2_load16(&a0[u], hp + (size_t)(16 + u) * 8192);
        VM_WAIT(8);
        DO_CHUNK(a1, 8)
        #pragma unroll
        for (int u = 0; u < 8; ++u) l2_load16(&a1[u], hp + (size_t)(24 + u) * 8192);
        VM_WAIT(8);
        DO_CHUNK(a0, 16)
        VM_WAIT(0);
        DO_CHUNK(a1, 24)
#undef DO_CHUNK

        // ---- fused cell ----
        unsigned short hv[4];
        #pragma unroll
        for (int j = 0; j < 4; ++j) {
            float gi = acc[0][j] + gq[j][0];
            float gf = acc[1][j] + gq[j][1];
            float gg = acc[2][j] + gq[j][2];
            float go = acc[3][j] + gq[j][3];
            float c2 = sigm_f(gf) * cc[j] + sigm_f(gi) * tanh_f(gg);
            cc[j] = c2;
            hv[j] = f2b(sigm_f(go) * tanh_f(c2));
        }
        STORE_H(t + 1, hv)
    }
    #undef STORE_H
}

// ---------------------------------------------------------------------------
// fp32 tiled GEMM (two small GEMMs): C = A @ B^T + bias
// ---------------------------------------------------------------------------
__global__ __launch_bounds__(256) void gemm_bt(
    const float* __restrict__ A, int lda,
    const float* __restrict__ Bm, int ldb,
    const float* __restrict__ bias,
    float* __restrict__ C, int ldc, int N, int K)
{
    const int BK = 16;
    __shared__ float As[BK][64];
    __shared__ float Bs[BK][64];

    const int tx = threadIdx.x, ty = threadIdx.y;
    const int tid = ty * 16 + tx;
    const int brow0 = blockIdx.y * 64;
    const int bcol0 = blockIdx.x * 64;

    const int e0   = tid * 4;
    const int la_r = e0 / BK;
    const int la_k = e0 % BK;

    const long long arow_base = (long long)(brow0 + la_r) * lda;
    const int bRowG = bcol0 + la_r;
    const bool bValid = (bRowG < N);
    const long long brow_base = (long long)bRowG * ldb;

    float acc[4][4] = {};

    for (int k0 = 0; k0 < K; k0 += BK) {
        float4 av = *(const float4*)(A + arow_base + k0 + la_k);
        float4 bv = make_float4(0.f, 0.f, 0.f, 0.f);
        if (bValid) bv = *(const float4*)(Bm + brow_base + k0 + la_k);

        As[la_k + 0][la_r] = av.x; As[la_k + 1][la_r] = av.y;
        As[la_k + 2][la_r] = av.z; As[la_k + 3][la_r] = av.w;
        Bs[la_k + 0][la_r] = bv.x; Bs[la_k + 1][la_r] = bv.y;
        Bs[la_k + 2][la_r] = bv.z; Bs[la_k + 3][la_r] = bv.w;
        __syncthreads();

        #pragma unroll
        for (int kk = 0; kk < BK; ++kk) {
            float af[4], bf[4];
            #pragma unroll
            for (int i = 0; i < 4; ++i) af[i] = As[kk][ty * 4 + i];
            #pragma unroll
            for (int j = 0; j < 4; ++j) bf[j] = Bs[kk][tx * 4 + j];
            #pragma unroll
            for (int i = 0; i < 4; ++i)
                #pragma unroll
                for (int j = 0; j < 4; ++j)
                    acc[i][j] = fmaf(af[i], bf[j], acc[i][j]);
        }
        __syncthreads();
    }

    #pragma unroll
    for (int i = 0; i < 4; ++i) {
        const int row = brow0 + ty * 4 + i;
        #pragma unroll
        for (int j = 0; j < 4; ++j) {
            const int col = bcol0 + tx * 4 + j;
            if (col < N) {
                float v = acc[i][j];
                if (bias) v += bias[col];
                C[(long long)row * ldc + col] = v;
            }
        }
    }
}

// ---------------------------------------------------------------------------
// f32 -> bf16 conversion with optional column slice + zero row padding
// ---------------------------------------------------------------------------
__global__ void conv2bf(const float* __restrict__ src, unsigned short* __restrict__ dst,
                        int rows, int rowsPad, int cols, int srcld, int srccol0)
{
    int i = blockIdx.x * blockDim.x + threadIdx.x;
    int c4n = cols >> 2;
    if (i >= rowsPad * c4n) return;
    int r = i / c4n, c4 = i % c4n;
    ushort4 o;
    if (r < rows) {
        float4 v = *(const float4*)(src + (long long)r * srcld + srccol0 + c4 * 4);
        o.x = f2b(v.x); o.y = f2b(v.y); o.z = f2b(v.z); o.w = f2b(v.w);
    } else {
        o = make_ushort4(0, 0, 0, 0);
    }
    *(ushort4*)(dst + (long long)r * cols + c4 * 4) = o;
}

// ---------------------------------------------------------------------------
// prep: gather indices + combined bias
// idxEmb ordered for gates rows r = t*B + b (gates layout [T,B,...])
// idxLog: blocked-hs row index, ar = slot*16384 + b  (slot = t+1)
// ---------------------------------------------------------------------------
__global__ void prep_kernel(const int* __restrict__ labels,
                            const float* __restrict__ b_ih,
                            const float* __restrict__ b_hh,
                            int* __restrict__ idxEmb,
                            int* __restrict__ idxLog,
                            float* __restrict__ bsum)
{
    int r = blockIdx.x * blockDim.x + threadIdx.x;
    if (r < B_ * T_) {
        {   // embedding gather: r = t*B + b
            int t = r >> 8, b = r & (B_ - 1);
            int tsrc = (t == 0) ? (T_ - 1) : (t - 1);
            idxEmb[r] = labels[b * T_ + tsrc];
        }
        {   // logits gather: r = b*T + t  -> hs slot t+1 (blocked)
            int b = r / T_, t = r % T_;
            idxLog[r] = (t + 1) * 16384 + b;
        }
    }
    if (r < G4_) bsum[r] = b_ih[r] + b_hh[r];
}

extern "C" void kernel_launch(void* const* d_in, const int* in_sizes, int n_in,
                              void* d_out, int out_size, void* d_ws, size_t ws_size,
                              hipStream_t stream)
{
    const float* X      = (const float*)d_in[0];
    const int*   labels = (const int*)  d_in[1];
    const float* W_f    = (const float*)d_in[2];
    const float* b_f    = (const float*)d_in[3];
    const float* emb    = (const float*)d_in[4];
    const float* W_ih   = (const float*)d_in[5];
    const float* W_hh   = (const float*)d_in[6];
    const float* b_ih   = (const float*)d_in[7];
    const float* b_hh   = (const float*)d_in[8];
    const float* W_out  = (const float*)d_in[9];
    const float* b_out  = (const float*)d_in[10];
    float* out = (float*)d_out;
    (void)in_sizes; (void)n_in; (void)out_size; (void)ws_size;

    char* ws = (char*)d_ws;
    size_t off = 0;
    auto alloc = [&](size_t bytes) {
        void* p = ws + off;
        off += (bytes + 255) & ~(size_t)255;
        return p;
    };
    unsigned short* emb_bf  = (unsigned short*)alloc((size_t)(V_ + 1) * E_ * 2);
    unsigned short* WihE_bf = (unsigned short*)alloc((size_t)G4_ * E_ * 2);
    unsigned short* Whh_bf  = (unsigned short*)alloc((size_t)G4_ * H_ * 2);
    unsigned short* Wout_bf = (unsigned short*)alloc((size_t)5120 * H_ * 2);
    unsigned short* hs_bf   = (unsigned short*)alloc((size_t)(T_ + 1) * 262144 * 2);
    float* features = (float*)alloc(B_ * E_ * 4);
    float* bsum     = (float*)alloc(G4_ * 4);
    int*   idxEmb   = (int*)  alloc(B_ * T_ * 4);
    int*   idxLog   = (int*)  alloc(B_ * T_ * 4);
    unsigned int* flags = (unsigned int*)alloc((size_t)(T_ + 1) * 256 * 2 * 4);

    // d_out reuse: gates [T,B,1024,4] at the front (fully consumed by the
    // recurrence before the logits GEMM overwrites d_out); baseMat in tail.
    float* gates   = out;
    float* baseMat = out + (size_t)B_ * T_ * G4_;   // 41.94M + 1.05M < 51.2M

    hipMemsetAsync(flags, 0, (size_t)(T_ + 1) * 256 * 2 * 4, stream);

    prep_kernel<<<(B_ * T_ + 255) / 256, 256, 0, stream>>>(
        labels, b_ih, b_hh, idxEmb, idxLog, bsum);

    {
        int n;
        n = (V_ + 1) * E_ / 4;
        conv2bf<<<(n + 255) / 256, 256, 0, stream>>>(emb, emb_bf, V_ + 1, V_ + 1, E_, E_, 0);
        n = G4_ * E_ / 4;
        conv2bf<<<(n + 255) / 256, 256, 0, stream>>>(W_ih, WihE_bf, G4_, G4_, E_, 2 * E_, E_);
        n = G4_ * H_ / 4;
        conv2bf<<<(n + 255) / 256, 256, 0, stream>>>(W_hh, Whh_bf, G4_, G4_, H_, H_, 0);
        n = 5120 * H_ / 4;
        conv2bf<<<(n + 255) / 256, 256, 0, stream>>>(W_out, Wout_bf, V_, 5120, H_, H_, 0);
    }

    dim3 thr(16, 16);

    // features = X @ W_f^T + b_f            [256,512] K=2048 (fp32)
    gemm_bt<<<dim3(E_ / 64, B_ / 64), thr, 0, stream>>>(
        X, IN_, W_f, IN_, b_f, features, E_, E_, IN_);

    // base = features @ W_ih[:, :E]^T + (b_ih + b_hh)   [256,4096] K=512 (fp32)
    gemm_bt<<<dim3(G4_ / 64, B_ / 64), thr, 0, stream>>>(
        features, E_, W_ih, 2 * E_, bsum, baseMat, G4_, G4_, E_);

    // gates[t,b,:] = gather(emb_bf) @ WihE^T + base[b], PERMUTED cols
    gemm_mfma<<<dim3(G4_ / 128, (B_ * T_) / 128), 256, 0, stream>>>(
        emb_bf, E_, 0, idxEmb, WihE_bf, E_, nullptr,
        baseMat, B_ - 1, G4_, gates, G4_, 1, G4_, E_);

    // ---- persistent recurrence (all 40 steps, one plain launch) ----
    {
        hipFuncSetAttribute((const void*)recur_persist,
                            hipFuncAttributeMaxDynamicSharedMemorySize, 131072);
        recur_persist<<<256, 256, 131072, stream>>>(hs_bf, Whh_bf, gates, flags);
    }

    // logits = gather(hs_bf blocked) @ W_out^T + b_out   [10240,5000] K=1024
    gemm_mfma<<<dim3(5120 / 128, (B_ * T_) / 128), 256, 0, stream>>>(
        hs_bf, 16, 1, idxLog, Wout_bf, H_, b_out,
        nullptr, 0, 0, out, V_, 0, V_, H_);
}

// Round 10
// 803.662 us; speedup vs baseline: 1.5408x; 1.0893x over previous
//
#include <hip/hip_runtime.h>
#include <hip/hip_bf16.h>
#include <math.h>

#define B_  256
#define T_  40
#define IN_ 2048
#define E_  512
#define H_  1024
#define V_  5000
#define G4_ 4096   // 4*H

typedef __bf16 bf16x8 __attribute__((ext_vector_type(8)));
typedef float  f32x4  __attribute__((ext_vector_type(4)));
typedef unsigned int u32x4 __attribute__((ext_vector_type(4)));

__device__ __forceinline__ float sigm_f(float x) { return 1.0f / (1.0f + __expf(-x)); }
__device__ __forceinline__ float tanh_f(float x) { return 1.0f - 2.0f / (1.0f + __expf(2.0f * x)); }

__device__ __forceinline__ unsigned short f2b(float x) {
    __hip_bfloat16 h = __float2bfloat16(x);
    return *reinterpret_cast<unsigned short*>(&h);
}
__device__ __forceinline__ float b2f(unsigned short u) {
    unsigned int v = (unsigned int)u << 16;
    return __builtin_bit_cast(float, v);
}

#define GLOAD_LDS(g, l) __builtin_amdgcn_global_load_lds(                     \
    (const __attribute__((address_space(1))) unsigned int*)(g),               \
    (__attribute__((address_space(3))) unsigned int*)(l), 16, 0, 0)

// normal (L2-cached) 16B load, manual vmcnt accounting via VM_WAIT
__device__ __forceinline__ void l2_load16(u32x4* dst, const unsigned short* p) {
    asm volatile("global_load_dwordx4 %0, %1, off" : "=v"(*dst) : "v"(p));
}
// LLC-coherent (cross-XCD) stores + poll
__device__ __forceinline__ void llc_store16(unsigned short* p, u32x4 v) {
    asm volatile("global_store_dwordx4 %0, %1, off sc0 sc1" :: "v"(p), "v"(v) : "memory");
}
__device__ __forceinline__ void llc_store4(unsigned int* p, unsigned int v) {
    asm volatile("global_store_dword %0, %1, off sc0 sc1" :: "v"(p), "v"(v) : "memory");
}
// poll load: waitcnt INSIDE the asm (compiler doesn't track asm loads)
__device__ __forceinline__ unsigned int llc_load4_wait(const unsigned int* p) {
    unsigned int v;
    asm volatile("global_load_dword %0, %1, off sc0 sc1\n\ts_waitcnt vmcnt(0)"
                 : "=v"(v) : "v"(p) : "memory");
    return v;
}
#define VM_WAIT(n) do {                                                       \
    asm volatile("s_waitcnt vmcnt(" #n ")" ::: "memory");                     \
    __builtin_amdgcn_sched_barrier(0);                                        \
} while (0)

// ---------------------------------------------------------------------------
// bf16 MFMA GEMM, 2-phase pipelined.
// C = gather(A) @ Bsel^T (+ bias) (+ addMat[(row&rowMask)*addStride + col])
// aBlocked: A stored as [kblk][256 rows][16] blocks (hs layout).
// bMapQ:    B row for (permuted) col c is worig = (c&3)*1024 + (c>>2).
// outBF16:  C is bf16, stored linearly in the permuted col space; addMat is
//           then also linear (baseMat pre-permuted). Else C is f32 + bias.
// 128x128 tile, BK=32, 256 thr = 4 waves, 16x16x32 MFMA. LDS 32 KB (2 buf).
// ---------------------------------------------------------------------------
__global__ __launch_bounds__(256) void gemm_mfma(
    const unsigned short* __restrict__ A, int lda, int aBlocked,
    const int* __restrict__ gidx,
    const unsigned short* __restrict__ Bm, int ldb, int bMapQ,
    const float* __restrict__ bias,
    const float* __restrict__ addMat, int rowMask, long long addStride,
    void* __restrict__ Cout, int ldc, int outBF16, int N, int K)
{
    __shared__ unsigned short As[2][128 * 32];
    __shared__ unsigned short Bs[2][128 * 32];

    const int tid  = threadIdx.x;
    const int wave = tid >> 6, lane = tid & 63;
    const int brow0 = blockIdx.y * 128, bcol0 = blockIdx.x * 128;
    const int wrow0 = (wave >> 1) * 64, wcol0 = (wave & 1) * 64;

    const int srow = lane >> 2;
    const int scol = (lane & 3) * 8;
    const size_t kstep = aBlocked ? 256 : 1;
    const unsigned short* pA[2];
    const unsigned short* pB[2];
    unsigned short* lA[2];
    unsigned short* lB[2];
    #pragma unroll
    for (int i = 0; i < 2; ++i) {
        int seg = wave * 2 + i;
        int row = seg * 16 + srow;
        long long ar = gidx ? (long long)gidx[brow0 + row] : (long long)(brow0 + row);
        if (aBlocked)
            pA[i] = A + ((size_t)ar << 4) + ((size_t)(scol >> 4) << 12) + (scol & 8);
        else
            pA[i] = A + (size_t)ar * lda + scol;
        int bc = bcol0 + row;
        long long wrow = bMapQ ? (long long)(((bc & 3) << 10) | (bc >> 2)) : bc;
        pB[i] = Bm + wrow * ldb + scol;
        lA[i] = &As[0][seg * 16 * 32];
        lB[i] = &Bs[0][seg * 16 * 32];
    }

    f32x4 acc[4][4] = {};
    const int foff = (lane & 15) * 32 + (lane >> 4) * 8;

    #define STAGE(buf, k0)                                                    \
        GLOAD_LDS(pA[0] + (size_t)(k0) * kstep, lA[0] + (buf) * 4096);        \
        GLOAD_LDS(pA[1] + (size_t)(k0) * kstep, lA[1] + (buf) * 4096);        \
        GLOAD_LDS(pB[0] + (k0), lB[0] + (buf) * 4096);                        \
        GLOAD_LDS(pB[1] + (k0), lB[1] + (buf) * 4096);

    STAGE(0, 0)
    asm volatile("s_waitcnt vmcnt(0)" ::: "memory");
    __syncthreads();

    int cur = 0;
    for (int k0 = 0; k0 < K; k0 += 32) {
        if (k0 + 32 < K) { STAGE(cur ^ 1, k0 + 32) }

        bf16x8 a[4], b[4];
        #pragma unroll
        for (int m = 0; m < 4; ++m)
            a[m] = *(const bf16x8*)&As[cur][(wrow0 + m * 16) * 32 + foff];
        #pragma unroll
        for (int n = 0; n < 4; ++n)
            b[n] = *(const bf16x8*)&Bs[cur][(wcol0 + n * 16) * 32 + foff];
        #pragma unroll
        for (int m = 0; m < 4; ++m)
            #pragma unroll
            for (int n = 0; n < 4; ++n)
                acc[m][n] = __builtin_amdgcn_mfma_f32_16x16x32_bf16(
                    a[m], b[n], acc[m][n], 0, 0, 0);

        asm volatile("s_waitcnt vmcnt(0)" ::: "memory");
        __syncthreads();
        cur ^= 1;
    }
    #undef STAGE

    #pragma unroll
    for (int m = 0; m < 4; ++m) {
        #pragma unroll
        for (int j = 0; j < 4; ++j) {
            int row = brow0 + wrow0 + m * 16 + (lane >> 4) * 4 + j;
            const float* addRow = addMat
                ? addMat + (long long)(row & rowMask) * addStride : nullptr;
            #pragma unroll
            for (int n = 0; n < 4; ++n) {
                int col = bcol0 + wcol0 + n * 16 + (lane & 15);
                if (col < N) {
                    float v = acc[m][n][j];
                    if (addRow) v += addRow[col];
                    if (outBF16) {
                        ((unsigned short*)Cout)[(long long)row * ldc + col] = f2b(v);
                    } else {
                        if (bias) v += bias[col];
                        ((float*)Cout)[(long long)row * ldc + col] = v;
                    }
                }
            }
        }
    }
}

// ---------------------------------------------------------------------------
// Persistent LSTM recurrence v5 (plain launch, 256 WGs x 256 thr).
// WG (mb = bid>>6, hb = bid&63): batch rows mb*64..+64, h-cols hb*16..+16.
// W_hh slice [64 gate-rows x 1024] bf16 LDS-resident (128 KB, XOR-swizzled).
// h BLOCKED: slot t = [64 kblk][256 row][16]; per-WG tile = one 2 KB span,
// stored by wave 0 as 128 coalesced 16B sc0sc1 stores via 3 KB LDS stage.
// gates: bf16 quad-interleaved [T][B][1024 hc][4] (8B/quad); PREFETCHED one
// step ahead (issued before step t's cell/store -> completes under the
// store-ack + flag + poll window). Sync: ONE flag/WG (plain sc0sc1 dword
// after wave-0's vmcnt(0) store-ack); consumers 64-lane parallel poll
// (lane l reads producer (mb,l)'s 4B flag, 256B total) + __all.
// ---------------------------------------------------------------------------
__global__ __launch_bounds__(256) void recur_persist(
    unsigned short* __restrict__ hs,          // slots 1..40, each 262144 elems
    const unsigned short* __restrict__ Whh,   // [4096,1024] bf16
    const unsigned short* __restrict__ gates, // [T,B,1024,4] bf16 (quad)
    unsigned int* __restrict__ flags)         // [(T+1)*256], zeroed
{
    extern __shared__ unsigned short lds[];   // [64][1024] bf16 = 128 KB
    __shared__ unsigned short hstage[64][24]; // store-coalescing scratch

    const int tid = threadIdx.x;
    const int w = tid >> 6, lane = tid & 63;
    const int mb = blockIdx.x >> 6;           // 0..3
    const int hb = blockIdx.x & 63;           // 0..63
    const int r16 = lane & 15, g4 = lane >> 4;
    const int sw7 = r16 & 7;
    const size_t SLOT = 262144;               // 64*256*16

    // per-lane coordinates
    const int arow = mb * 64 + w * 16 + r16;         // A row (blocked layout)
    const size_t abase = ((size_t)arow << 4) + ((g4 >> 1) << 12) + ((g4 & 1) << 3);
    const int orow0 = mb * 64 + w * 16 + g4 * 4;     // output rows +j
    const int hc    = hb * 16 + r16;                 // h column
    const int lrow0 = w * 16 + g4 * 4;               // local tile row
    // gates quad base (elements): (t*256 + row)*4096 + hc*4
    const size_t gq_base = ((size_t)orow0 << 12) + ((size_t)hc << 2);

    // ---- issue step-0 gates loads (plain, compiler-tracked) ----
    ushort4 gqc[4], gqn[4];
    #pragma unroll
    for (int j = 0; j < 4; ++j)
        gqc[j] = *(const ushort4*)(gates + gq_base + ((size_t)j << 12));

    // ---- stage W_hh slice into LDS once (wave w = gate q) ----
    {
        const int q = w;
        for (int r = 0; r < 16; ++r) {
            const int g = q * 16 + r;
            const unsigned short* rowsrc =
                Whh + ((size_t)q * 1024 + hb * 16 + r) * H_;
            #pragma unroll
            for (int half = 0; half < 2; ++half) {
                int gran = (half * 64 + lane) ^ (g & 7);
                GLOAD_LDS(rowsrc + gran * 8, &lds[g * 1024 + half * 512]);
            }
        }
    }
    asm volatile("s_waitcnt vmcnt(0)" ::: "memory");
    __syncthreads();

    int qbase[4];
    #pragma unroll
    for (int q = 0; q < 4; ++q) qbase[q] = (q * 16 + r16) << 11;

    float cc[4];

    // store path: stage tile in LDS; wave 0 issues 128 x 16B sc0sc1 stores,
    // vmcnt(0) ack, then ONE flag (lane 0). No barrier after.
    #define STORE_H(T1, HV)                                                   \
    {                                                                         \
        _Pragma("unroll")                                                     \
        for (int j = 0; j < 4; ++j) hstage[lrow0 + j][r16] = HV[j];           \
        __syncthreads();                                                      \
        if (w == 0) {                                                         \
            unsigned short* dst0 = hs + (size_t)(T1) * SLOT +                 \
                (((size_t)hb * 256 + mb * 64) << 4);                          \
            _Pragma("unroll")                                                 \
            for (int s = 0; s < 2; ++s) {                                     \
                int idx = s * 64 + lane;                                      \
                u32x4 v = *(const u32x4*)&hstage[idx >> 1][(idx & 1) * 8];    \
                llc_store16(dst0 + (size_t)idx * 8, v);                       \
            }                                                                 \
            asm volatile("s_waitcnt vmcnt(0)" ::: "memory");                  \
            if (lane == 0)                                                    \
                llc_store4(flags + ((T1) << 8) + (mb << 6) + hb, 1u);         \
        }                                                                     \
    }

    // ---- step 0: h0 = 0 -> gates only; prefetch step-1 gates first ----
    {
        #pragma unroll
        for (int j = 0; j < 4; ++j)
            gqn[j] = *(const ushort4*)(gates + (1ull << 20) + gq_base +
                                       ((size_t)j << 12));
        unsigned short hv[4];
        #pragma unroll
        for (int j = 0; j < 4; ++j) {
            float gi = b2f(gqc[j].x), gg = b2f(gqc[j].z), go = b2f(gqc[j].w);
            float c2 = sigm_f(gi) * tanh_f(gg);
            cc[j] = c2;
            hv[j] = f2b(sigm_f(go) * tanh_f(c2));
        }
        STORE_H(1, hv)
        #pragma unroll
        for (int j = 0; j < 4; ++j) gqc[j] = gqn[j];
    }

    // ---- steps 1..39 ----
    for (int t = 1; t < T_; ++t) {
        // 64-lane parallel poll: lane l watches producer WG (mb, l)'s flag
        {
            const unsigned int* fp = flags + ((size_t)t << 8) + (mb << 6) + lane;
            for (;;) {
                unsigned int fv = llc_load4_wait(fp);
                if (__all(fv == 1u)) break;
                __builtin_amdgcn_s_sleep(1);
            }
        }
        __builtin_amdgcn_sched_barrier(0);

        const unsigned short* hp = hs + (size_t)t * SLOT + abase;

        u32x4 a0[8], a1[8];
        #pragma unroll
        for (int u = 0; u < 8; ++u) l2_load16(&a0[u], hp + (size_t)u * 8192);
        #pragma unroll
        for (int u = 0; u < 8; ++u) l2_load16(&a1[u], hp + (size_t)(8 + u) * 8192);

        f32x4 acc[4] = {};

#define DO_CHUNK(BUF, KSB)                                                    \
        _Pragma("unroll")                                                     \
        for (int u = 0; u < 8; ++u) {                                         \
            bf16x8 a8 = __builtin_bit_cast(bf16x8, BUF[u]);                   \
            _Pragma("unroll")                                                 \
            for (int q = 0; q < 4; ++q) {                                     \
                int off = qbase[q] + (((((KSB) + u) * 4 + g4) ^ sw7) << 4);   \
                bf16x8 b8 = *(const bf16x8*)((const char*)lds + off);         \
                acc[q] = __builtin_amdgcn_mfma_f32_16x16x32_bf16(             \
                    a8, b8, acc[q], 0, 0, 0);                                 \
            }                                                                 \
        }

        VM_WAIT(8);
        DO_CHUNK(a0, 0)
        #pragma unroll
        for (int u = 0; u < 8; ++u) l2_load16(&a0[u], hp + (size_t)(16 + u) * 8192);
        VM_WAIT(8);
        DO_CHUNK(a1, 8)
        #pragma unroll
        for (int u = 0; u < 8; ++u) l2_load16(&a1[u], hp + (size_t)(24 + u) * 8192);
        VM_WAIT(8);
        DO_CHUNK(a0, 16)
        VM_WAIT(0);
        DO_CHUNK(a1, 24)
#undef DO_CHUNK

        // prefetch next step's gates (completes under store-ack + poll)
        if (t + 1 < T_) {
            #pragma unroll
            for (int j = 0; j < 4; ++j)
                gqn[j] = *(const ushort4*)(gates +
                    ((size_t)(t + 1) << 20) + gq_base + ((size_t)j << 12));
        }

        // ---- fused cell ----
        unsigned short hv[4];
        #pragma unroll
        for (int j = 0; j < 4; ++j) {
            float gi = acc[0][j] + b2f(gqc[j].x);
            float gf = acc[1][j] + b2f(gqc[j].y);
            float gg = acc[2][j] + b2f(gqc[j].z);
            float go = acc[3][j] + b2f(gqc[j].w);
            float c2 = sigm_f(gf) * cc[j] + sigm_f(gi) * tanh_f(gg);
            cc[j] = c2;
            hv[j] = f2b(sigm_f(go) * tanh_f(c2));
        }
        STORE_H(t + 1, hv)
        #pragma unroll
        for (int j = 0; j < 4; ++j) gqc[j] = gqn[j];
    }
    #undef STORE_H
}

// ---------------------------------------------------------------------------
// fp32 tiled GEMM (two small GEMMs): C = A @ B^T + bias, optional permuted
// column store: col j -> ((j&1023)<<2) | (j>>10)   (for baseMat).
// ---------------------------------------------------------------------------
__global__ __launch_bounds__(256) void gemm_bt(
    const float* __restrict__ A, int lda,
    const float* __restrict__ Bm, int ldb,
    const float* __restrict__ bias,
    float* __restrict__ C, int ldc, int permuteC, int N, int K)
{
    const int BK = 16;
    __shared__ float As[BK][64];
    __shared__ float Bs[BK][64];

    const int tx = threadIdx.x, ty = threadIdx.y;
    const int tid = ty * 16 + tx;
    const int brow0 = blockIdx.y * 64;
    const int bcol0 = blockIdx.x * 64;

    const int e0   = tid * 4;
    const int la_r = e0 / BK;
    const int la_k = e0 % BK;

    const long long arow_base = (long long)(brow0 + la_r) * lda;
    const int bRowG = bcol0 + la_r;
    const bool bValid = (bRowG < N);
    const long long brow_base = (long long)bRowG * ldb;

    float acc[4][4] = {};

    for (int k0 = 0; k0 < K; k0 += BK) {
        float4 av = *(const float4*)(A + arow_base + k0 + la_k);
        float4 bv = make_float4(0.f, 0.f, 0.f, 0.f);
        if (bValid) bv = *(const float4*)(Bm + brow_base + k0 + la_k);

        As[la_k + 0][la_r] = av.x; As[la_k + 1][la_r] = av.y;
        As[la_k + 2][la_r] = av.z; As[la_k + 3][la_r] = av.w;
        Bs[la_k + 0][la_r] = bv.x; Bs[la_k + 1][la_r] = bv.y;
        Bs[la_k + 2][la_r] = bv.z; Bs[la_k + 3][la_r] = bv.w;
        __syncthreads();

        #pragma unroll
        for (int kk = 0; kk < BK; ++kk) {
            float af[4], bf[4];
            #pragma unroll
            for (int i = 0; i < 4; ++i) af[i] = As[kk][ty * 4 + i];
            #pragma unroll
            for (int j = 0; j < 4; ++j) bf[j] = Bs[kk][tx * 4 + j];
            #pragma unroll
            for (int i = 0; i < 4; ++i)
                #pragma unroll
                for (int j = 0; j < 4; ++j)
                    acc[i][j] = fmaf(af[i], bf[j], acc[i][j]);
        }
        __syncthreads();
    }

    #pragma unroll
    for (int i = 0; i < 4; ++i) {
        const int row = brow0 + ty * 4 + i;
        #pragma unroll
        for (int j = 0; j < 4; ++j) {
            const int col = bcol0 + tx * 4 + j;
            if (col < N) {
                float v = acc[i][j];
                if (bias) v += bias[col];
                int cidx = permuteC ? (((col & 1023) << 2) | (col >> 10)) : col;
                C[(long long)row * ldc + cidx] = v;
            }
        }
    }
}

// ---------------------------------------------------------------------------
// f32 -> bf16 conversion with optional column slice + zero row padding
// ---------------------------------------------------------------------------
__global__ void conv2bf(const float* __restrict__ src, unsigned short* __restrict__ dst,
                        int rows, int rowsPad, int cols, int srcld, int srccol0)
{
    int i = blockIdx.x * blockDim.x + threadIdx.x;
    int c4n = cols >> 2;
    if (i >= rowsPad * c4n) return;
    int r = i / c4n, c4 = i % c4n;
    ushort4 o;
    if (r < rows) {
        float4 v = *(const float4*)(src + (long long)r * srcld + srccol0 + c4 * 4);
        o.x = f2b(v.x); o.y = f2b(v.y); o.z = f2b(v.z); o.w = f2b(v.w);
    } else {
        o = make_ushort4(0, 0, 0, 0);
    }
    *(ushort4*)(dst + (long long)r * cols + c4 * 4) = o;
}

// ---------------------------------------------------------------------------
// prep: gather indices + combined bias
// idxEmb ordered for gates rows r = t*B + b
// idxLog: blocked-hs row index, ar = slot*16384 + b  (slot = t+1)
// ---------------------------------------------------------------------------
__global__ void prep_kernel(const int* __restrict__ labels,
                            const float* __restrict__ b_ih,
                            const float* __restrict__ b_hh,
                            int* __restrict__ idxEmb,
                            int* __restrict__ idxLog,
                            float* __restrict__ bsum)
{
    int r = blockIdx.x * blockDim.x + threadIdx.x;
    if (r < B_ * T_) {
        {   // embedding gather: r = t*B + b
            int t = r >> 8, b = r & (B_ - 1);
            int tsrc = (t == 0) ? (T_ - 1) : (t - 1);
            idxEmb[r] = labels[b * T_ + tsrc];
        }
        {   // logits gather: r = b*T + t  -> hs slot t+1 (blocked)
            int b = r / T_, t = r % T_;
            idxLog[r] = (t + 1) * 16384 + b;
        }
    }
    if (r < G4_) bsum[r] = b_ih[r] + b_hh[r];
}

extern "C" void kernel_launch(void* const* d_in, const int* in_sizes, int n_in,
                              void* d_out, int out_size, void* d_ws, size_t ws_size,
                              hipStream_t stream)
{
    const float* X      = (const float*)d_in[0];
    const int*   labels = (const int*)  d_in[1];
    const float* W_f    = (const float*)d_in[2];
    const float* b_f    = (const float*)d_in[3];
    const float* emb    = (const float*)d_in[4];
    const float* W_ih   = (const float*)d_in[5];
    const float* W_hh   = (const float*)d_in[6];
    const float* b_ih   = (const float*)d_in[7];
    const float* b_hh   = (const float*)d_in[8];
    const float* W_out  = (const float*)d_in[9];
    const float* b_out  = (const float*)d_in[10];
    float* out = (float*)d_out;
    (void)in_sizes; (void)n_in; (void)out_size; (void)ws_size;

    char* ws = (char*)d_ws;
    size_t off = 0;
    auto alloc = [&](size_t bytes) {
        void* p = ws + off;
        off += (bytes + 255) & ~(size_t)255;
        return p;
    };
    unsigned short* emb_bf  = (unsigned short*)alloc((size_t)(V_ + 1) * E_ * 2);
    unsigned short* WihE_bf = (unsigned short*)alloc((size_t)G4_ * E_ * 2);
    unsigned short* Whh_bf  = (unsigned short*)alloc((size_t)G4_ * H_ * 2);
    unsigned short* Wout_bf = (unsigned short*)alloc((size_t)5120 * H_ * 2);
    unsigned short* hs_bf   = (unsigned short*)alloc((size_t)(T_ + 1) * 262144 * 2);
    float* features = (float*)alloc(B_ * E_ * 4);
    float* bsum     = (float*)alloc(G4_ * 4);
    int*   idxEmb   = (int*)  alloc(B_ * T_ * 4);
    int*   idxLog   = (int*)  alloc(B_ * T_ * 4);
    unsigned int* flags = (unsigned int*)alloc((size_t)(T_ + 1) * 256 * 4);

    // d_out reuse: gates_bf [T,B,1024,4] bf16 (84 MB = 21M floats) at front,
    // consumed by the recurrence before the logits GEMM overwrites d_out;
    // baseMat (permuted, 4 MB) in the tail.
    unsigned short* gates_bf = (unsigned short*)out;
    float* baseMat = out + 22 * 1024 * 1024;        // 22M + 1M < 51.2M floats

    hipMemsetAsync(flags, 0, (size_t)(T_ + 1) * 256 * 4, stream);

    prep_kernel<<<(B_ * T_ + 255) / 256, 256, 0, stream>>>(
        labels, b_ih, b_hh, idxEmb, idxLog, bsum);

    {
        int n;
        n = (V_ + 1) * E_ / 4;
        conv2bf<<<(n + 255) / 256, 256, 0, stream>>>(emb, emb_bf, V_ + 1, V_ + 1, E_, E_, 0);
        n = G4_ * E_ / 4;
        conv2bf<<<(n + 255) / 256, 256, 0, stream>>>(W_ih, WihE_bf, G4_, G4_, E_, 2 * E_, E_);
        n = G4_ * H_ / 4;
        conv2bf<<<(n + 255) / 256, 256, 0, stream>>>(W_hh, Whh_bf, G4_, G4_, H_, H_, 0);
        n = 5120 * H_ / 4;
        conv2bf<<<(n + 255) / 256, 256, 0, stream>>>(W_out, Wout_bf, V_, 5120, H_, H_, 0);
    }

    dim3 thr(16, 16);

    // features = X @ W_f^T + b_f            [256,512] K=2048 (fp32)
    gemm_bt<<<dim3(E_ / 64, B_ / 64), thr, 0, stream>>>(
        X, IN_, W_f, IN_, b_f, features, E_, 0, E_, IN_);

    // baseMat (PERMUTED cols) = features @ W_ih[:, :E]^T + (b_ih + b_hh)
    gemm_bt<<<dim3(G4_ / 64, B_ / 64), thr, 0, stream>>>(
        features, E_, W_ih, 2 * E_, bsum, baseMat, G4_, 1, G4_, E_);

    // gates_bf[t,b,hc,q] = gather(emb_bf) @ W_ihE(q-mapped)^T + baseMat_perm[b]
    gemm_mfma<<<dim3(G4_ / 128, (B_ * T_) / 128), 256, 0, stream>>>(
        emb_bf, E_, 0, idxEmb, WihE_bf, E_, 1, nullptr,
        baseMat, B_ - 1, G4_, gates_bf, G4_, 1, G4_, E_);

    // ---- persistent recurrence (all 40 steps, one plain launch) ----
    {
        hipFuncSetAttribute((const void*)recur_persist,
                            hipFuncAttributeMaxDynamicSharedMemorySize, 131072);
        recur_persist<<<256, 256, 131072, stream>>>(hs_bf, Whh_bf, gates_bf, flags);
    }

    // logits = gather(hs_bf blocked) @ W_out^T + b_out   [10240,5000] K=1024
    gemm_mfma<<<dim3(5120 / 128, (B_ * T_) / 128), 256, 0, stream>>>(
        hs_bf, 16, 1, idxLog, Wout_bf, H_, 0, b_out,
        nullptr, 0, 0, out, V_, 0, V_, H_);
}